// Round 1
// 2032.383 us; speedup vs baseline: 1.3439x; 1.3439x over previous
//
#include <hip/hip_runtime.h>
#include <math.h>

#define TT 1024
#define BB 2
#define DD 1024
#define NH 16
#define NKV 4
#define HD 64
#define ED 4096
#define LL 4
#define VV 32000
#define QKVS 1536   // fused qkv row stride (fp32 elements)

typedef __bf16 bf16x8 __attribute__((ext_vector_type(8)));
typedef float f32x4 __attribute__((ext_vector_type(4)));

__device__ inline unsigned short f2bf(float f) {
  unsigned u = __float_as_uint(f);
  u += 0x7fffu + ((u >> 16) & 1u);   // round-to-nearest-even
  return (unsigned short)(u >> 16);
}

#define GLL16(gsrc, ldst)                                                            \
  __builtin_amdgcn_global_load_lds((const __attribute__((address_space(1))) void*)(gsrc), \
                                   (__attribute__((address_space(3))) void*)(ldst), 16, 0, 0)

// ---------------- weight conversion: contiguous fp32 -> bf16 ----------------
__global__ void convw_kernel(const float* __restrict__ src, unsigned short* __restrict__ dst) {
  size_t i = (size_t)blockIdx.x * blockDim.x + threadIdx.x;
  float4 v = ((const float4*)src)[i];
  uint2 o;
  o.x = f2bf(v.x) | ((unsigned)f2bf(v.y) << 16);
  o.y = f2bf(v.z) | ((unsigned)f2bf(v.w) << 16);
  ((uint2*)dst)[i] = o;
}

// fused QKV weights: per layer dst [1536][1024] = [q(1024) ; k(256) ; v(256)]
__global__ void conv_qkv_kernel(const float* __restrict__ qw, const float* __restrict__ kw,
                                const float* __restrict__ vw, unsigned short* __restrict__ dst) {
  size_t i = (size_t)blockIdx.x * blockDim.x + threadIdx.x;
  size_t e = i * 4;
  int l = (int)(e / (QKVS * 1024));
  int rem = (int)(e - (size_t)l * (QKVS * 1024));
  int row = rem >> 10;
  int col = rem & 1023;
  const float* src;
  if (row < 1024) src = qw + (((size_t)l << 20) + ((size_t)row << 10)) + col;
  else if (row < 1280) src = kw + (((size_t)l << 18) + ((size_t)(row - 1024) << 10)) + col;
  else src = vw + (((size_t)l << 18) + ((size_t)(row - 1280) << 10)) + col;
  float4 v = *(const float4*)src;
  uint2 o;
  o.x = f2bf(v.x) | ((unsigned)f2bf(v.y) << 16);
  o.y = f2bf(v.z) | ((unsigned)f2bf(v.w) << 16);
  ((uint2*)dst)[i] = o;
}

// fused W1/W3: per layer dst [8192][1024] = [w1(4096) ; w3(4096)]
__global__ void conv_w13_kernel(const float* __restrict__ w1, const float* __restrict__ w3,
                                unsigned short* __restrict__ dst) {
  size_t i = (size_t)blockIdx.x * blockDim.x + threadIdx.x;
  size_t e = i * 4;
  int l = (int)(e >> 23);              // / (8192*1024)
  int rem = (int)(e & ((1u << 23) - 1));
  int row = rem >> 10;
  int col = rem & 1023;
  const float* src;
  if (row < 4096) src = w1 + (((size_t)l << 22) + ((size_t)row << 10)) + col;
  else src = w3 + (((size_t)l << 22) + ((size_t)(row - 4096) << 10)) + col;
  float4 v = *(const float4*)src;
  uint2 o;
  o.x = f2bf(v.x) | ((unsigned)f2bf(v.y) << 16);
  o.y = f2bf(v.z) | ((unsigned)f2bf(v.w) << 16);
  ((uint2*)dst)[i] = o;
}

// ---------------- embedding gather ----------------
__global__ void embed_kernel(const int* __restrict__ ids, const float* __restrict__ emb,
                             float* __restrict__ x) {
  int row = blockIdx.x;
  int id = ids[row];
  const float4* src = (const float4*)(emb + (size_t)id * DD);
  float4* dst = (float4*)(x + (size_t)row * DD);
  dst[threadIdx.x] = src[threadIdx.x];
}

// ---------------- rmsnorm (fp32 in -> bf16 out) ----------------
__global__ __launch_bounds__(256) void rmsnorm_kernel(const float* __restrict__ x,
                                                      const float* __restrict__ wgt,
                                                      unsigned short* __restrict__ out) {
  int row = blockIdx.x;
  int tid = threadIdx.x;
  float4 v = *(const float4*)(x + (size_t)row * DD + tid * 4);
  float ss = v.x * v.x + v.y * v.y + v.z * v.z + v.w * v.w;
#pragma unroll
  for (int off = 32; off >= 1; off >>= 1) ss += __shfl_xor(ss, off);
  __shared__ float part[4];
  if ((tid & 63) == 0) part[tid >> 6] = ss;
  __syncthreads();
  ss = part[0] + part[1] + part[2] + part[3];
  float sc = rsqrtf(ss * (1.0f / DD) + 1e-6f);
  float4 wv = *(const float4*)(wgt + tid * 4);
  uint2 o;
  o.x = f2bf(v.x * wv.x * sc) | ((unsigned)f2bf(v.y * wv.y * sc) << 16);
  o.y = f2bf(v.z * wv.z * sc) | ((unsigned)f2bf(v.w * wv.w * sc) << 16);
  *(uint2*)(out + (size_t)row * DD + tid * 4) = o;
}

// ---------------- GEMM (bf16 A, bf16 W): C[M,N] (+)= A[M,K] * W[N,K]^T ----------------
// m97 structure: 128x128 tile, BK=32, linear LDS, global_load_lds x16 for both operands.
// Block order: n-major linear index + XCD chunk swizzle so m-tiles sharing a W panel
// co-reside on one XCD's L2.
template <int EPI>
__global__ __launch_bounds__(256) void gemm_bb(const unsigned short* __restrict__ A,
                                               const unsigned short* __restrict__ W,
                                               float* __restrict__ C, int M, int N, int K) {
  __shared__ unsigned short As[128 * 32];
  __shared__ unsigned short Bs[128 * 32];
  const int tid = threadIdx.x;
  const int lane = tid & 63;
  const int w = tid >> 6;
  const int wm = (w >> 1) * 64;
  const int wn = (w & 1) * 64;
  const int l15 = lane & 15;
  const int quad = lane >> 4;
  const int q8 = quad * 8;

  const int nby = gridDim.y;
  const int nwg = gridDim.x * nby;
  int orig = blockIdx.x * nby + blockIdx.y;   // n-major: consecutive blocks share a W panel
  int swz = orig;
  if ((nwg & 7) == 0) {
    int cpx = nwg >> 3;
    swz = (orig & 7) * cpx + (orig >> 3);
  }
  const int mBase = (swz % nby) * 128;
  const int nBase = (swz / nby) * 128;

  const unsigned short* Ab = A + (size_t)mBase * K;
  const unsigned short* Wb = W + (size_t)nBase * K;
  const int r0 = tid >> 2;            // chunk i=0 row
  const int c8 = (tid & 3) * 8;       // chunk col (elements)

  f32x4 acc[4][4] = {};

  for (int kt = 0; kt < K; kt += 32) {
    __syncthreads();
    // stage A: 128x32 bf16, 512 chunks of 16B, 2 issues of 256 threads
    GLL16(Ab + (size_t)r0 * K + kt + c8, As + (w * 64) * 8);
    GLL16(Ab + (size_t)(r0 + 64) * K + kt + c8, As + (256 + w * 64) * 8);
    // stage B
    GLL16(Wb + (size_t)r0 * K + kt + c8, Bs + (w * 64) * 8);
    GLL16(Wb + (size_t)(r0 + 64) * K + kt + c8, Bs + (256 + w * 64) * 8);
    __syncthreads();   // compiler emits s_waitcnt vmcnt(0) before s_barrier
    bf16x8 af[4], bfv[4];
#pragma unroll
    for (int ms = 0; ms < 4; ms++)
      af[ms] = *(const bf16x8*)&As[(wm + ms * 16 + l15) * 32 + q8];
#pragma unroll
    for (int ns = 0; ns < 4; ns++)
      bfv[ns] = *(const bf16x8*)&Bs[(wn + ns * 16 + l15) * 32 + q8];
#pragma unroll
    for (int ms = 0; ms < 4; ms++)
#pragma unroll
      for (int ns = 0; ns < 4; ns++)
        acc[ms][ns] = __builtin_amdgcn_mfma_f32_16x16x32_bf16(af[ms], bfv[ns], acc[ms][ns], 0, 0, 0);
  }
#pragma unroll
  for (int ms = 0; ms < 4; ms++)
#pragma unroll
    for (int ns = 0; ns < 4; ns++)
#pragma unroll
      for (int r = 0; r < 4; r++) {
        int row = mBase + wm + ms * 16 + quad * 4 + r;
        int col = nBase + wn + ns * 16 + l15;
        size_t idx = (size_t)row * N + col;
        if (EPI == 0) C[idx] = acc[ms][ns][r];
        else C[idx] += acc[ms][ns][r];
      }
}

// ---------------- GEMM fallback: bf16 A * fp32 W (converted in staging) ----------------
template <int EPI>
__global__ __launch_bounds__(256) void gemm_bt(const unsigned short* __restrict__ A,
                                               const float* __restrict__ W,
                                               float* __restrict__ C, int M, int N, int K) {
  __shared__ unsigned short As[128 * 40];
  __shared__ unsigned short Bs[128 * 40];
  const int tid = threadIdx.x;
  const int lane = tid & 63;
  const int w = tid >> 6;
  const int wm = (w >> 1) * 64;
  const int wn = (w & 1) * 64;
  const int l15 = lane & 15;
  const int quad = lane >> 4;
  const int q8 = quad * 8;

  const int nby = gridDim.y;
  const int nwg = gridDim.x * nby;
  int orig = blockIdx.x * nby + blockIdx.y;
  int swz = orig;
  if ((nwg & 7) == 0) {
    int cpx = nwg >> 3;
    swz = (orig & 7) * cpx + (orig >> 3);
  }
  const int mBase = (swz % nby) * 128;
  const int nBase = (swz / nby) * 128;

  f32x4 acc[4][4] = {};

  for (int kt = 0; kt < K; kt += 32) {
    __syncthreads();
#pragma unroll
    for (int i = 0; i < 2; i++) {
      int chunk = tid + 256 * i;
      int r = chunk >> 2, c8 = (chunk & 3) * 8;
      uint4 v = *(const uint4*)(A + (size_t)(mBase + r) * K + kt + c8);
      *(uint4*)&As[r * 40 + c8] = v;
    }
#pragma unroll
    for (int i = 0; i < 2; i++) {
      int chunk = tid + 256 * i;
      int r = chunk >> 2, c8 = (chunk & 3) * 8;
      const float4* wp = (const float4*)(W + (size_t)(nBase + r) * K + kt + c8);
      float4 f0 = wp[0], f1 = wp[1];
      uint4 v;
      v.x = f2bf(f0.x) | ((unsigned)f2bf(f0.y) << 16);
      v.y = f2bf(f0.z) | ((unsigned)f2bf(f0.w) << 16);
      v.z = f2bf(f1.x) | ((unsigned)f2bf(f1.y) << 16);
      v.w = f2bf(f1.z) | ((unsigned)f2bf(f1.w) << 16);
      *(uint4*)&Bs[r * 40 + c8] = v;
    }
    __syncthreads();
    bf16x8 af[4], bfv[4];
#pragma unroll
    for (int ms = 0; ms < 4; ms++)
      af[ms] = *(const bf16x8*)&As[(wm + ms * 16 + l15) * 40 + q8];
#pragma unroll
    for (int ns = 0; ns < 4; ns++)
      bfv[ns] = *(const bf16x8*)&Bs[(wn + ns * 16 + l15) * 40 + q8];
#pragma unroll
    for (int ms = 0; ms < 4; ms++)
#pragma unroll
      for (int ns = 0; ns < 4; ns++)
        acc[ms][ns] = __builtin_amdgcn_mfma_f32_16x16x32_bf16(af[ms], bfv[ns], acc[ms][ns], 0, 0, 0);
  }
#pragma unroll
  for (int ms = 0; ms < 4; ms++)
#pragma unroll
    for (int ns = 0; ns < 4; ns++)
#pragma unroll
      for (int r = 0; r < 4; r++) {
        int row = mBase + wm + ms * 16 + quad * 4 + r;
        int col = nBase + wn + ns * 16 + l15;
        size_t idx = (size_t)row * N + col;
        if (EPI == 0) C[idx] = acc[ms][ns][r];
        else C[idx] += acc[ms][ns][r];
      }
}

// ---------------- RoPE (in-place, fp32, strided rows) ----------------
__global__ void rope_kernel(float* __restrict__ buf, int nh, int stride) {
  int e = blockIdx.x * blockDim.x + threadIdx.x;
  int per_row = nh * 32;
  int row = e / per_row;
  int rem = e - row * per_row;
  int hh = rem >> 5;
  int d = rem & 31;
  int t = row & (TT - 1);
  float invf = __expf(-(float)d * 0.28782313662f);  // 10000^(-d/32)
  float ang = (float)t * invf;
  float sv, cv;
  sincosf(ang, &sv, &cv);
  float* p = buf + (size_t)row * stride + hh * 64 + d;
  float x1 = p[0], x2 = p[32];
  p[0] = x1 * cv - x2 * sv;
  p[32] = x2 * cv + x1 * sv;
}

// ---------------- flash attention (bf16 MFMA, fp32 softmax) ----------------
// Q/K/V live in the fused qkv buffer with row stride QKVS.
__global__ __launch_bounds__(256) void attn_fwd(const float* __restrict__ Q,
                                                const float* __restrict__ Kb,
                                                const float* __restrict__ Vb,
                                                unsigned short* __restrict__ O) {
  __shared__ unsigned short Qs[64 * 72];  // reused as P after Q frags are in regs
  __shared__ unsigned short Ks[64 * 72];
  __shared__ unsigned short Vt[64 * 72];  // transposed V: [d][key]
  const int tid = threadIdx.x;
  const int lane = tid & 63;
  const int w = tid >> 6;
  const int l15 = lane & 15;
  const int quad = lane >> 4;
  const int q8 = quad * 8;
  const int bh = blockIdx.x;
  const int b = bh / NH, h = bh % NH;
  const int hkv = h >> 2;
  const int qb = blockIdx.y;

#pragma unroll
  for (int i = 0; i < 4; i++) {  // stage Q tile 64x64
    int cc = tid + 256 * i;
    int r = cc >> 4, d4 = (cc & 15) * 4;
    float4 v = *(const float4*)(Q + (size_t)(b * TT + qb * 64 + r) * QKVS + h * HD + d4);
    uint2 p;
    p.x = f2bf(v.x) | ((unsigned)f2bf(v.y) << 16);
    p.y = f2bf(v.z) | ((unsigned)f2bf(v.w) << 16);
    *(uint2*)&Qs[r * 72 + d4] = p;
  }
  __syncthreads();
  bf16x8 qa0 = *(const bf16x8*)&Qs[(w * 16 + l15) * 72 + q8];
  bf16x8 qa1 = *(const bf16x8*)&Qs[(w * 16 + l15) * 72 + 32 + q8];

  f32x4 oacc[4] = {};
  float m_i[4], l_i[4];
#pragma unroll
  for (int r = 0; r < 4; r++) { m_i[r] = -1e30f; l_i[r] = 0.f; }

  for (int kb = 0; kb <= qb; kb++) {
    __syncthreads();
#pragma unroll
    for (int i = 0; i < 4; i++) {  // stage K (row-major) and V (transposed)
      int cc = tid + 256 * i;
      int r = cc >> 4, d4 = (cc & 15) * 4;
      size_t grow = (size_t)(b * TT + kb * 64 + r) * QKVS + hkv * HD + d4;
      float4 kv = *(const float4*)(Kb + grow);
      uint2 p;
      p.x = f2bf(kv.x) | ((unsigned)f2bf(kv.y) << 16);
      p.y = f2bf(kv.z) | ((unsigned)f2bf(kv.w) << 16);
      *(uint2*)&Ks[r * 72 + d4] = p;
      float4 vv = *(const float4*)(Vb + grow);
      Vt[(d4 + 0) * 72 + r] = f2bf(vv.x);
      Vt[(d4 + 1) * 72 + r] = f2bf(vv.y);
      Vt[(d4 + 2) * 72 + r] = f2bf(vv.z);
      Vt[(d4 + 3) * 72 + r] = f2bf(vv.w);
    }
    __syncthreads();
    // S = Q K^T : 16 q-rows x 64 keys per wave
    f32x4 s[4];
#pragma unroll
    for (int ns = 0; ns < 4; ns++) {
      bf16x8 k0 = *(const bf16x8*)&Ks[(ns * 16 + l15) * 72 + q8];
      bf16x8 k1 = *(const bf16x8*)&Ks[(ns * 16 + l15) * 72 + 32 + q8];
      f32x4 z = {};
      z = __builtin_amdgcn_mfma_f32_16x16x32_bf16(qa0, k0, z, 0, 0, 0);
      s[ns] = __builtin_amdgcn_mfma_f32_16x16x32_bf16(qa1, k1, z, 0, 0, 0);
    }
#pragma unroll
    for (int ns = 0; ns < 4; ns++)
#pragma unroll
      for (int r = 0; r < 4; r++) {
        float sv = s[ns][r] * 0.125f;  // 1/sqrt(64)
        if (kb == qb) {
          int qloc = w * 16 + quad * 4 + r;
          int kloc = ns * 16 + l15;
          if (kloc > qloc) sv = -1e30f;
        }
        s[ns][r] = sv;
      }
    // online softmax; row r lives in the 16-lane group (quad fixed)
    float p[4][4];
    float alpha[4];
#pragma unroll
    for (int r = 0; r < 4; r++) {
      float mx = fmaxf(fmaxf(s[0][r], s[1][r]), fmaxf(s[2][r], s[3][r]));
#pragma unroll
      for (int off = 1; off < 16; off <<= 1) mx = fmaxf(mx, __shfl_xor(mx, off));
      float mnew = fmaxf(m_i[r], mx);
      alpha[r] = __expf(m_i[r] - mnew);
      float rs = 0.f;
#pragma unroll
      for (int ns = 0; ns < 4; ns++) {
        p[ns][r] = __expf(s[ns][r] - mnew);
        rs += p[ns][r];
      }
#pragma unroll
      for (int off = 1; off < 16; off <<= 1) rs += __shfl_xor(rs, off);
      l_i[r] = l_i[r] * alpha[r] + rs;
      m_i[r] = mnew;
    }
#pragma unroll
    for (int ds = 0; ds < 4; ds++)
#pragma unroll
      for (int r = 0; r < 4; r++) oacc[ds][r] *= alpha[r];
    // P: C-layout regs -> LDS (A-layout read). Per-wave private 16-row strip.
#pragma unroll
    for (int ns = 0; ns < 4; ns++)
#pragma unroll
      for (int r = 0; r < 4; r++)
        Qs[(w * 16 + quad * 4 + r) * 72 + ns * 16 + l15] = f2bf(p[ns][r]);
    __syncthreads();
    bf16x8 pa0 = *(const bf16x8*)&Qs[(w * 16 + l15) * 72 + q8];
    bf16x8 pa1 = *(const bf16x8*)&Qs[(w * 16 + l15) * 72 + 32 + q8];
#pragma unroll
    for (int ds = 0; ds < 4; ds++) {
      bf16x8 v0 = *(const bf16x8*)&Vt[(ds * 16 + l15) * 72 + q8];
      bf16x8 v1 = *(const bf16x8*)&Vt[(ds * 16 + l15) * 72 + 32 + q8];
      oacc[ds] = __builtin_amdgcn_mfma_f32_16x16x32_bf16(pa0, v0, oacc[ds], 0, 0, 0);
      oacc[ds] = __builtin_amdgcn_mfma_f32_16x16x32_bf16(pa1, v1, oacc[ds], 0, 0, 0);
    }
  }
#pragma unroll
  for (int ds = 0; ds < 4; ds++)
#pragma unroll
    for (int r = 0; r < 4; r++) {
      int row = qb * 64 + w * 16 + quad * 4 + r;
      int col = h * HD + ds * 16 + l15;
      O[(size_t)(b * TT + row) * DD + col] = f2bf(oacc[ds][r] / l_i[r]);
    }
}

// ---------------- SwiGLU on fused [2048][8192] = [gate|up] buffer ----------------
__global__ void swiglu_kernel(const float* __restrict__ G, unsigned short* __restrict__ out) {
  size_t i = (size_t)blockIdx.x * blockDim.x + threadIdx.x;  // one float4 of gate
  size_t i4 = i * 4;
  int row = (int)(i4 >> 12);       // / 4096
  int col = (int)(i4 & 4095);
  float4 g = *(const float4*)(G + (size_t)row * 8192 + col);
  float4 u = *(const float4*)(G + (size_t)row * 8192 + 4096 + col);
  float r0 = g.x / (1.f + __expf(-g.x)) * u.x;
  float r1 = g.y / (1.f + __expf(-g.y)) * u.y;
  float r2 = g.z / (1.f + __expf(-g.z)) * u.z;
  float r3 = g.w / (1.f + __expf(-g.w)) * u.w;
  uint2 o;
  o.x = f2bf(r0) | ((unsigned)f2bf(r1) << 16);
  o.y = f2bf(r2) | ((unsigned)f2bf(r3) << 16);
  ((uint2*)out)[i] = o;
}

extern "C" void kernel_launch(void* const* d_in, const int* in_sizes, int n_in,
                              void* d_out, int out_size, void* d_ws, size_t ws_size,
                              hipStream_t stream) {
  const int* ids = (const int*)d_in[0];
  const float* emb = (const float*)d_in[1];
  const float* ln1 = (const float*)d_in[2];
  const float* qw = (const float*)d_in[3];
  const float* kw = (const float*)d_in[4];
  const float* vw = (const float*)d_in[5];
  const float* ow = (const float*)d_in[6];
  const float* ln2 = (const float*)d_in[7];
  const float* w1 = (const float*)d_in[8];
  const float* w2 = (const float*)d_in[9];
  const float* w3 = (const float*)d_in[10];
  const float* lnf = (const float*)d_in[11];

  const int BT = BB * TT;  // 2048
  const size_t MB = 1024ull * 1024ull;
  char* ob = (char*)d_out;  // 250 MiB; logits written only at the very end

  // d_out scratch layout (all dead before the logits GEMM writes d_out):
  float* guf = (float*)ob;                                   // 64 MiB  [2048][8192] fp32
  unsigned short* hb2 = (unsigned short*)(ob + 64 * MB);     // 16 MiB  [2048][4096] bf16
  unsigned short* qkvb = (unsigned short*)(ob + 80 * MB);    // 12 MiB  L x [1536][1024] bf16
  unsigned short* owb = (unsigned short*)(ob + 92 * MB);     //  8 MiB  L x [1024][1024] bf16
  unsigned short* w13b = (unsigned short*)(ob + 100 * MB);   // 64 MiB  L x [8192][1024] bf16
  unsigned short* w2b = (unsigned short*)(ob + 164 * MB);    // 32 MiB  L x [1024][4096] bf16
  // ends at 196 MiB; 196..250 free for fallback activations

  char* wb = (char*)d_ws;
  unsigned short* hb = (unsigned short*)wb;  // 4 MiB (ws must be >= 4 MiB)
  float* x;
  float* qkv;
  unsigned short* ao;
  if (ws_size >= 28 * MB) {
    x = (float*)(wb + 4 * MB);              // 8 MiB
    qkv = (float*)(wb + 12 * MB);           // 12 MiB [2048][1536] fp32
    ao = (unsigned short*)(wb + 24 * MB);   // 4 MiB
  } else {
    x = (float*)(ob + 196 * MB);
    qkv = (float*)(ob + 204 * MB);
    ao = (unsigned short*)(ob + 216 * MB);
  }
  // bf16 embedding for the logits GEMM must stay live while d_out is written ->
  // only possible in workspace.
  const bool bf16_logits = (ws_size >= 92 * MB);
  unsigned short* embb = bf16_logits ? (unsigned short*)(wb + 28 * MB) : nullptr;  // 62.5 MiB

  // ---- one-shot weight conversion (fp32 -> bf16, fused layouts) ----
  conv_qkv_kernel<<<6144, 256, 0, stream>>>(qw, kw, vw, qkvb);
  convw_kernel<<<4096, 256, 0, stream>>>(ow, owb);
  conv_w13_kernel<<<32768, 256, 0, stream>>>(w1, w3, w13b);
  convw_kernel<<<16384, 256, 0, stream>>>(w2, w2b);
  if (bf16_logits) convw_kernel<<<32000, 256, 0, stream>>>(emb, embb);

  embed_kernel<<<BT, 256, 0, stream>>>(ids, emb, x);
  for (int l = 0; l < LL; l++) {
    rmsnorm_kernel<<<BT, 256, 0, stream>>>(x, ln1 + l * DD, hb);
    gemm_bb<0><<<dim3(QKVS / 128, BT / 128), 256, 0, stream>>>(
        hb, qkvb + (size_t)l * QKVS * DD, qkv, BT, QKVS, DD);
    rope_kernel<<<(BT * NH * 32) / 256, 256, 0, stream>>>(qkv, NH, QKVS);
    rope_kernel<<<(BT * NKV * 32) / 256, 256, 0, stream>>>(qkv + 1024, NKV, QKVS);
    attn_fwd<<<dim3(BB * NH, TT / 64), 256, 0, stream>>>(qkv, qkv + 1024, qkv + 1280, ao);
    gemm_bb<1><<<dim3(DD / 128, BT / 128), 256, 0, stream>>>(
        ao, owb + (size_t)l * DD * DD, x, BT, DD, DD);
    rmsnorm_kernel<<<BT, 256, 0, stream>>>(x, ln2 + l * DD, hb);
    gemm_bb<0><<<dim3((2 * ED) / 128, BT / 128), 256, 0, stream>>>(
        hb, w13b + (size_t)l * 2 * ED * DD, guf, BT, 2 * ED, DD);
    swiglu_kernel<<<(BT * ED / 4) / 256, 256, 0, stream>>>(guf, hb2);
    gemm_bb<1><<<dim3(DD / 128, BT / 128), 256, 0, stream>>>(
        hb2, w2b + (size_t)l * DD * ED, x, BT, DD, ED);
  }
  rmsnorm_kernel<<<BT, 256, 0, stream>>>(x, lnf, hb);
  if (bf16_logits) {
    gemm_bb<0><<<dim3(VV / 128, BT / 128), 256, 0, stream>>>(hb, embb, (float*)d_out, BT, VV, DD);
  } else {
    gemm_bt<0><<<dim3(VV / 128, BT / 128), 256, 0, stream>>>(hb, emb, (float*)d_out, BT, VV, DD);
  }
}

// Round 2
// 1844.738 us; speedup vs baseline: 1.4806x; 1.1017x over previous
//
#include <hip/hip_runtime.h>
#include <math.h>

#define TT 1024
#define BB 2
#define DD 1024
#define NH 16
#define NKV 4
#define HD 64
#define ED 4096
#define LL 4
#define VV 32000
#define QKVS 1536   // fused qkv row stride (fp32 elements)

typedef __bf16 bf16x8 __attribute__((ext_vector_type(8)));
typedef float f32x4 __attribute__((ext_vector_type(4)));

__device__ inline unsigned short f2bf(float f) {
  unsigned u = __float_as_uint(f);
  u += 0x7fffu + ((u >> 16) & 1u);   // round-to-nearest-even
  return (unsigned short)(u >> 16);
}

#define GLL16(gsrc, ldst)                                                            \
  __builtin_amdgcn_global_load_lds((const __attribute__((address_space(1))) void*)(gsrc), \
                                   (__attribute__((address_space(3))) void*)(ldst), 16, 0, 0)

// ---------------- weight conversion: contiguous fp32 -> bf16 ----------------
__global__ void convw_kernel(const float* __restrict__ src, unsigned short* __restrict__ dst) {
  size_t i = (size_t)blockIdx.x * blockDim.x + threadIdx.x;
  float4 v = ((const float4*)src)[i];
  uint2 o;
  o.x = f2bf(v.x) | ((unsigned)f2bf(v.y) << 16);
  o.y = f2bf(v.z) | ((unsigned)f2bf(v.w) << 16);
  ((uint2*)dst)[i] = o;
}

// fused QKV weights: per layer dst [1536][1024] = [q(1024) ; k(256) ; v(256)]
__global__ void conv_qkv_kernel(const float* __restrict__ qw, const float* __restrict__ kw,
                                const float* __restrict__ vw, unsigned short* __restrict__ dst) {
  size_t i = (size_t)blockIdx.x * blockDim.x + threadIdx.x;
  size_t e = i * 4;
  int l = (int)(e / (QKVS * 1024));
  int rem = (int)(e - (size_t)l * (QKVS * 1024));
  int row = rem >> 10;
  int col = rem & 1023;
  const float* src;
  if (row < 1024) src = qw + (((size_t)l << 20) + ((size_t)row << 10)) + col;
  else if (row < 1280) src = kw + (((size_t)l << 18) + ((size_t)(row - 1024) << 10)) + col;
  else src = vw + (((size_t)l << 18) + ((size_t)(row - 1280) << 10)) + col;
  float4 v = *(const float4*)src;
  uint2 o;
  o.x = f2bf(v.x) | ((unsigned)f2bf(v.y) << 16);
  o.y = f2bf(v.z) | ((unsigned)f2bf(v.w) << 16);
  ((uint2*)dst)[i] = o;
}

// fused W1/W3, 16-row interleaved: dst row r (of 8192): grp=r>>4, f=(grp>>1)*16+(r&15);
// grp even -> w1[f], grp odd -> w3[f].  This puts gate/up for the same f-column in the
// same lane of the GEMM accumulator (frag pairs ns={0,1},{2,3}) -> in-register SwiGLU.
__global__ void conv_w13_kernel(const float* __restrict__ w1, const float* __restrict__ w3,
                                unsigned short* __restrict__ dst) {
  size_t i = (size_t)blockIdx.x * blockDim.x + threadIdx.x;
  size_t e = i * 4;
  int l = (int)(e >> 23);              // / (8192*1024)
  int rem = (int)(e & ((1u << 23) - 1));
  int r = rem >> 10;
  int col = rem & 1023;
  int grp = r >> 4;
  int f = (grp >> 1) * 16 + (r & 15);
  const float* base = (grp & 1) ? w3 : w1;
  const float* src = base + (((size_t)l << 22) + ((size_t)f << 10)) + col;
  float4 v = *(const float4*)src;
  uint2 o;
  o.x = f2bf(v.x) | ((unsigned)f2bf(v.y) << 16);
  o.y = f2bf(v.z) | ((unsigned)f2bf(v.w) << 16);
  ((uint2*)dst)[i] = o;
}

// ---------------- embedding gather ----------------
__global__ void embed_kernel(const int* __restrict__ ids, const float* __restrict__ emb,
                             float* __restrict__ x) {
  int row = blockIdx.x;
  int id = ids[row];
  const float4* src = (const float4*)(emb + (size_t)id * DD);
  float4* dst = (float4*)(x + (size_t)row * DD);
  dst[threadIdx.x] = src[threadIdx.x];
}

// ---------------- rmsnorm (fp32 in -> bf16 out) ----------------
__global__ __launch_bounds__(256) void rmsnorm_kernel(const float* __restrict__ x,
                                                      const float* __restrict__ wgt,
                                                      unsigned short* __restrict__ out) {
  int row = blockIdx.x;
  int tid = threadIdx.x;
  float4 v = *(const float4*)(x + (size_t)row * DD + tid * 4);
  float ss = v.x * v.x + v.y * v.y + v.z * v.z + v.w * v.w;
#pragma unroll
  for (int off = 32; off >= 1; off >>= 1) ss += __shfl_xor(ss, off);
  __shared__ float part[4];
  if ((tid & 63) == 0) part[tid >> 6] = ss;
  __syncthreads();
  ss = part[0] + part[1] + part[2] + part[3];
  float sc = rsqrtf(ss * (1.0f / DD) + 1e-6f);
  float4 wv = *(const float4*)(wgt + tid * 4);
  uint2 o;
  o.x = f2bf(v.x * wv.x * sc) | ((unsigned)f2bf(v.y * wv.y * sc) << 16);
  o.y = f2bf(v.z * wv.z * sc) | ((unsigned)f2bf(v.w * wv.w * sc) << 16);
  *(uint2*)(out + (size_t)row * DD + tid * 4) = o;
}

// ---------------- x += p0 + p1 (split-K combine + residual) ----------------
__global__ void add2_kernel(float* __restrict__ x, const float* __restrict__ p0,
                            const float* __restrict__ p1) {
  size_t i = (size_t)blockIdx.x * blockDim.x + threadIdx.x;
  float4 a = ((const float4*)x)[i];
  float4 b = ((const float4*)p0)[i];
  float4 c = ((const float4*)p1)[i];
  a.x += b.x + c.x; a.y += b.y + c.y; a.z += b.z + c.z; a.w += b.w + c.w;
  ((float4*)x)[i] = a;
}

// ---------------- GEMM (bf16 A, bf16 W): C[M,N] (+)= A[M,K] * W[N,K]^T ----------------
// m97 structure: 128x128 tile, BK=32, linear LDS, global_load_lds x16 for both operands.
// XCD swizzle on the HARDWARE dispatch id (bid = by*gx+bx, XCD = bid%8): each XCD gets a
// contiguous n-major chunk so m-tiles sharing a W panel co-reside in one XCD's L2.
// EPI 0: store fp32 (split-K aware: C += z*M*N), 1: accumulate, 2: SwiGLU -> bf16 O2.
template <int EPI>
__global__ __launch_bounds__(256) void gemm_bb(const unsigned short* __restrict__ A,
                                               const unsigned short* __restrict__ W,
                                               float* __restrict__ C,
                                               unsigned short* __restrict__ O2,
                                               int M, int N, int K) {
  __shared__ unsigned short As[128 * 32];
  __shared__ unsigned short Bs[128 * 32];
  const int tid = threadIdx.x;
  const int lane = tid & 63;
  const int w = tid >> 6;
  const int wm = (w >> 1) * 64;
  const int wn = (w & 1) * 64;
  const int l15 = lane & 15;
  const int quad = lane >> 4;
  const int q8 = quad * 8;

  const int nby = gridDim.y;
  const int nwg = gridDim.x * nby;
  const int bid = blockIdx.y * gridDim.x + blockIdx.x;  // hardware linear order (x fastest)
  int wk = bid;
  if ((nwg & 7) == 0) {
    int cpx = nwg >> 3;
    wk = (bid & 7) * cpx + (bid >> 3);   // XCD bid%8 -> contiguous work chunk
  }
  const int mBase = (wk % nby) * 128;    // n-major: consecutive wk share a W panel
  const int nBase = (wk / nby) * 128;

  const int ksl = K / gridDim.z;         // split-K slice (z=1 -> full K)
  const int kb0 = blockIdx.z * ksl;
  if (EPI == 0) C += (size_t)blockIdx.z * M * N;

  const unsigned short* Ab = A + (size_t)mBase * K;
  const unsigned short* Wb = W + (size_t)nBase * K;
  const int r0 = tid >> 2;            // staging row for chunk 0
  const int c8 = (tid & 3) * 8;       // staging col (elements)

  f32x4 acc[4][4] = {};

  for (int kt = kb0; kt < kb0 + ksl; kt += 32) {
    __syncthreads();
    GLL16(Ab + (size_t)r0 * K + kt + c8, As + (w * 64) * 8);
    GLL16(Ab + (size_t)(r0 + 64) * K + kt + c8, As + (256 + w * 64) * 8);
    GLL16(Wb + (size_t)r0 * K + kt + c8, Bs + (w * 64) * 8);
    GLL16(Wb + (size_t)(r0 + 64) * K + kt + c8, Bs + (256 + w * 64) * 8);
    __syncthreads();
    bf16x8 af[4], bfv[4];
#pragma unroll
    for (int ms = 0; ms < 4; ms++)
      af[ms] = *(const bf16x8*)&As[(wm + ms * 16 + l15) * 32 + q8];
#pragma unroll
    for (int ns = 0; ns < 4; ns++)
      bfv[ns] = *(const bf16x8*)&Bs[(wn + ns * 16 + l15) * 32 + q8];
#pragma unroll
    for (int ms = 0; ms < 4; ms++)
#pragma unroll
      for (int ns = 0; ns < 4; ns++)
        acc[ms][ns] = __builtin_amdgcn_mfma_f32_16x16x32_bf16(af[ms], bfv[ns], acc[ms][ns], 0, 0, 0);
  }

  if (EPI == 2) {
    // interleaved gate/up: frag ns even = gate, ns odd = up, same f in same lane
    const int fBase = ((nBase + wn) >> 5) * 16;
#pragma unroll
    for (int ms = 0; ms < 4; ms++)
#pragma unroll
      for (int r = 0; r < 4; r++) {
        int row = mBase + wm + ms * 16 + quad * 4 + r;
#pragma unroll
        for (int pp = 0; pp < 2; pp++) {
          float g = acc[ms][pp * 2][r];
          float u = acc[ms][pp * 2 + 1][r];
          float res = g / (1.f + __expf(-g)) * u;
          O2[(size_t)row * ED + fBase + pp * 16 + l15] = f2bf(res);
        }
      }
  } else {
#pragma unroll
    for (int ms = 0; ms < 4; ms++)
#pragma unroll
      for (int ns = 0; ns < 4; ns++)
#pragma unroll
        for (int r = 0; r < 4; r++) {
          int row = mBase + wm + ms * 16 + quad * 4 + r;
          int col = nBase + wn + ns * 16 + l15;
          size_t idx = (size_t)row * N + col;
          if (EPI == 0) C[idx] = acc[ms][ns][r];
          else C[idx] += acc[ms][ns][r];
        }
  }
}

// ---------------- GEMM fallback: bf16 A * fp32 W (converted in staging) ----------------
template <int EPI>
__global__ __launch_bounds__(256) void gemm_bt(const unsigned short* __restrict__ A,
                                               const float* __restrict__ W,
                                               float* __restrict__ C, int M, int N, int K) {
  __shared__ unsigned short As[128 * 40];
  __shared__ unsigned short Bs[128 * 40];
  const int tid = threadIdx.x;
  const int lane = tid & 63;
  const int w = tid >> 6;
  const int wm = (w >> 1) * 64;
  const int wn = (w & 1) * 64;
  const int l15 = lane & 15;
  const int quad = lane >> 4;
  const int q8 = quad * 8;

  const int nby = gridDim.y;
  const int nwg = gridDim.x * nby;
  const int bid = blockIdx.y * gridDim.x + blockIdx.x;
  int wk = bid;
  if ((nwg & 7) == 0) {
    int cpx = nwg >> 3;
    wk = (bid & 7) * cpx + (bid >> 3);
  }
  const int mBase = (wk % nby) * 128;
  const int nBase = (wk / nby) * 128;

  f32x4 acc[4][4] = {};

  for (int kt = 0; kt < K; kt += 32) {
    __syncthreads();
#pragma unroll
    for (int i = 0; i < 2; i++) {
      int chunk = tid + 256 * i;
      int r = chunk >> 2, cc8 = (chunk & 3) * 8;
      uint4 v = *(const uint4*)(A + (size_t)(mBase + r) * K + kt + cc8);
      *(uint4*)&As[r * 40 + cc8] = v;
    }
#pragma unroll
    for (int i = 0; i < 2; i++) {
      int chunk = tid + 256 * i;
      int r = chunk >> 2, cc8 = (chunk & 3) * 8;
      const float4* wp = (const float4*)(W + (size_t)(nBase + r) * K + kt + cc8);
      float4 f0 = wp[0], f1 = wp[1];
      uint4 v;
      v.x = f2bf(f0.x) | ((unsigned)f2bf(f0.y) << 16);
      v.y = f2bf(f0.z) | ((unsigned)f2bf(f0.w) << 16);
      v.z = f2bf(f1.x) | ((unsigned)f2bf(f1.y) << 16);
      v.w = f2bf(f1.z) | ((unsigned)f2bf(f1.w) << 16);
      *(uint4*)&Bs[r * 40 + cc8] = v;
    }
    __syncthreads();
    bf16x8 af[4], bfv[4];
#pragma unroll
    for (int ms = 0; ms < 4; ms++)
      af[ms] = *(const bf16x8*)&As[(wm + ms * 16 + l15) * 40 + q8];
#pragma unroll
    for (int ns = 0; ns < 4; ns++)
      bfv[ns] = *(const bf16x8*)&Bs[(wn + ns * 16 + l15) * 40 + q8];
#pragma unroll
    for (int ms = 0; ms < 4; ms++)
#pragma unroll
      for (int ns = 0; ns < 4; ns++)
        acc[ms][ns] = __builtin_amdgcn_mfma_f32_16x16x32_bf16(af[ms], bfv[ns], acc[ms][ns], 0, 0, 0);
  }
#pragma unroll
  for (int ms = 0; ms < 4; ms++)
#pragma unroll
    for (int ns = 0; ns < 4; ns++)
#pragma unroll
      for (int r = 0; r < 4; r++) {
        int row = mBase + wm + ms * 16 + quad * 4 + r;
        int col = nBase + wn + ns * 16 + l15;
        size_t idx = (size_t)row * N + col;
        if (EPI == 0) C[idx] = acc[ms][ns][r];
        else C[idx] += acc[ms][ns][r];
      }
}

// ---------------- RoPE (in-place, fp32, strided rows) ----------------
__global__ void rope_kernel(float* __restrict__ buf, int nh, int stride) {
  int e = blockIdx.x * blockDim.x + threadIdx.x;
  int per_row = nh * 32;
  int row = e / per_row;
  int rem = e - row * per_row;
  int hh = rem >> 5;
  int d = rem & 31;
  int t = row & (TT - 1);
  float invf = __expf(-(float)d * 0.28782313662f);  // 10000^(-d/32)
  float ang = (float)t * invf;
  float sv, cv;
  sincosf(ang, &sv, &cv);
  float* p = buf + (size_t)row * stride + hh * 64 + d;
  float x1 = p[0], x2 = p[32];
  p[0] = x1 * cv - x2 * sv;
  p[32] = x2 * cv + x1 * sv;
}

// ---------------- flash attention (bf16 MFMA, fp32 softmax) ----------------
__global__ __launch_bounds__(256) void attn_fwd(const float* __restrict__ Q,
                                                const float* __restrict__ Kb,
                                                const float* __restrict__ Vb,
                                                unsigned short* __restrict__ O) {
  __shared__ unsigned short Qs[64 * 72];  // reused as P after Q frags are in regs
  __shared__ unsigned short Ks[64 * 72];
  __shared__ unsigned short Vt[64 * 72];  // transposed V: [d][key]
  const int tid = threadIdx.x;
  const int lane = tid & 63;
  const int w = tid >> 6;
  const int l15 = lane & 15;
  const int quad = lane >> 4;
  const int q8 = quad * 8;
  const int bh = blockIdx.x;
  const int b = bh / NH, h = bh % NH;
  const int hkv = h >> 2;
  const int qb = blockIdx.y;

#pragma unroll
  for (int i = 0; i < 4; i++) {  // stage Q tile 64x64
    int cc = tid + 256 * i;
    int r = cc >> 4, d4 = (cc & 15) * 4;
    float4 v = *(const float4*)(Q + (size_t)(b * TT + qb * 64 + r) * QKVS + h * HD + d4);
    uint2 p;
    p.x = f2bf(v.x) | ((unsigned)f2bf(v.y) << 16);
    p.y = f2bf(v.z) | ((unsigned)f2bf(v.w) << 16);
    *(uint2*)&Qs[r * 72 + d4] = p;
  }
  __syncthreads();
  bf16x8 qa0 = *(const bf16x8*)&Qs[(w * 16 + l15) * 72 + q8];
  bf16x8 qa1 = *(const bf16x8*)&Qs[(w * 16 + l15) * 72 + 32 + q8];

  f32x4 oacc[4] = {};
  float m_i[4], l_i[4];
#pragma unroll
  for (int r = 0; r < 4; r++) { m_i[r] = -1e30f; l_i[r] = 0.f; }

  for (int kb = 0; kb <= qb; kb++) {
    __syncthreads();
#pragma unroll
    for (int i = 0; i < 4; i++) {  // stage K (row-major) and V (transposed)
      int cc = tid + 256 * i;
      int r = cc >> 4, d4 = (cc & 15) * 4;
      size_t grow = (size_t)(b * TT + kb * 64 + r) * QKVS + hkv * HD + d4;
      float4 kv = *(const float4*)(Kb + grow);
      uint2 p;
      p.x = f2bf(kv.x) | ((unsigned)f2bf(kv.y) << 16);
      p.y = f2bf(kv.z) | ((unsigned)f2bf(kv.w) << 16);
      *(uint2*)&Ks[r * 72 + d4] = p;
      float4 vv = *(const float4*)(Vb + grow);
      Vt[(d4 + 0) * 72 + r] = f2bf(vv.x);
      Vt[(d4 + 1) * 72 + r] = f2bf(vv.y);
      Vt[(d4 + 2) * 72 + r] = f2bf(vv.z);
      Vt[(d4 + 3) * 72 + r] = f2bf(vv.w);
    }
    __syncthreads();
    // S = Q K^T : 16 q-rows x 64 keys per wave
    f32x4 s[4];
#pragma unroll
    for (int ns = 0; ns < 4; ns++) {
      bf16x8 k0 = *(const bf16x8*)&Ks[(ns * 16 + l15) * 72 + q8];
      bf16x8 k1 = *(const bf16x8*)&Ks[(ns * 16 + l15) * 72 + 32 + q8];
      f32x4 z = {};
      z = __builtin_amdgcn_mfma_f32_16x16x32_bf16(qa0, k0, z, 0, 0, 0);
      s[ns] = __builtin_amdgcn_mfma_f32_16x16x32_bf16(qa1, k1, z, 0, 0, 0);
    }
#pragma unroll
    for (int ns = 0; ns < 4; ns++)
#pragma unroll
      for (int r = 0; r < 4; r++) {
        float sv = s[ns][r] * 0.125f;  // 1/sqrt(64)
        if (kb == qb) {
          int qloc = w * 16 + quad * 4 + r;
          int kloc = ns * 16 + l15;
          if (kloc > qloc) sv = -1e30f;
        }
        s[ns][r] = sv;
      }
    // online softmax; row r lives in the 16-lane group (quad fixed)
    float p[4][4];
    float alpha[4];
#pragma unroll
    for (int r = 0; r < 4; r++) {
      float mx = fmaxf(fmaxf(s[0][r], s[1][r]), fmaxf(s[2][r], s[3][r]));
#pragma unroll
      for (int off = 1; off < 16; off <<= 1) mx = fmaxf(mx, __shfl_xor(mx, off));
      float mnew = fmaxf(m_i[r], mx);
      alpha[r] = __expf(m_i[r] - mnew);
      float rs = 0.f;
#pragma unroll
      for (int ns = 0; ns < 4; ns++) {
        p[ns][r] = __expf(s[ns][r] - mnew);
        rs += p[ns][r];
      }
#pragma unroll
      for (int off = 1; off < 16; off <<= 1) rs += __shfl_xor(rs, off);
      l_i[r] = l_i[r] * alpha[r] + rs;
      m_i[r] = mnew;
    }
#pragma unroll
    for (int ds = 0; ds < 4; ds++)
#pragma unroll
      for (int r = 0; r < 4; r++) oacc[ds][r] *= alpha[r];
    // P: C-layout regs -> LDS (A-layout read). Per-wave private 16-row strip.
#pragma unroll
    for (int ns = 0; ns < 4; ns++)
#pragma unroll
      for (int r = 0; r < 4; r++)
        Qs[(w * 16 + quad * 4 + r) * 72 + ns * 16 + l15] = f2bf(p[ns][r]);
    __syncthreads();
    bf16x8 pa0 = *(const bf16x8*)&Qs[(w * 16 + l15) * 72 + q8];
    bf16x8 pa1 = *(const bf16x8*)&Qs[(w * 16 + l15) * 72 + 32 + q8];
#pragma unroll
    for (int ds = 0; ds < 4; ds++) {
      bf16x8 v0 = *(const bf16x8*)&Vt[(ds * 16 + l15) * 72 + q8];
      bf16x8 v1 = *(const bf16x8*)&Vt[(ds * 16 + l15) * 72 + 32 + q8];
      oacc[ds] = __builtin_amdgcn_mfma_f32_16x16x32_bf16(pa0, v0, oacc[ds], 0, 0, 0);
      oacc[ds] = __builtin_amdgcn_mfma_f32_16x16x32_bf16(pa1, v1, oacc[ds], 0, 0, 0);
    }
  }
#pragma unroll
  for (int ds = 0; ds < 4; ds++)
#pragma unroll
    for (int r = 0; r < 4; r++) {
      int row = qb * 64 + w * 16 + quad * 4 + r;
      int col = h * HD + ds * 16 + l15;
      O[(size_t)(b * TT + row) * DD + col] = f2bf(oacc[ds][r] / l_i[r]);
    }
}

extern "C" void kernel_launch(void* const* d_in, const int* in_sizes, int n_in,
                              void* d_out, int out_size, void* d_ws, size_t ws_size,
                              hipStream_t stream) {
  const int* ids = (const int*)d_in[0];
  const float* emb = (const float*)d_in[1];
  const float* ln1 = (const float*)d_in[2];
  const float* qw = (const float*)d_in[3];
  const float* kw = (const float*)d_in[4];
  const float* vw = (const float*)d_in[5];
  const float* ow = (const float*)d_in[6];
  const float* ln2 = (const float*)d_in[7];
  const float* w1 = (const float*)d_in[8];
  const float* w2 = (const float*)d_in[9];
  const float* w3 = (const float*)d_in[10];
  const float* lnf = (const float*)d_in[11];

  const int BT = BB * TT;  // 2048
  const size_t MB = 1024ull * 1024ull;
  char* ob = (char*)d_out;  // 250 MiB; logits written only at the very end

  // d_out scratch layout (all dead before the logits GEMM writes d_out):
  float* guf = (float*)ob;                                   // 64 MiB  (w2 split-K partials)
  unsigned short* hb2 = (unsigned short*)(ob + 64 * MB);     // 16 MiB  [2048][4096] bf16
  unsigned short* qkvb = (unsigned short*)(ob + 80 * MB);    // 12 MiB  L x [1536][1024] bf16
  unsigned short* owb = (unsigned short*)(ob + 92 * MB);     //  8 MiB  L x [1024][1024] bf16
  unsigned short* w13b = (unsigned short*)(ob + 100 * MB);   // 64 MiB  L x [8192][1024] bf16
  unsigned short* w2b = (unsigned short*)(ob + 164 * MB);    // 32 MiB  L x [1024][4096] bf16
  // ends at 196 MiB; 196..250 free for fallback activations

  char* wb = (char*)d_ws;
  unsigned short* hb = (unsigned short*)wb;  // 4 MiB (ws must be >= 4 MiB)
  float* x;
  float* qkv;
  unsigned short* ao;
  if (ws_size >= 28 * MB) {
    x = (float*)(wb + 4 * MB);              // 8 MiB
    qkv = (float*)(wb + 12 * MB);           // 12 MiB [2048][1536] fp32
    ao = (unsigned short*)(wb + 24 * MB);   // 4 MiB
  } else {
    x = (float*)(ob + 196 * MB);
    qkv = (float*)(ob + 204 * MB);
    ao = (unsigned short*)(ob + 216 * MB);
  }
  const bool bf16_logits = (ws_size >= 92 * MB);
  unsigned short* embb = bf16_logits ? (unsigned short*)(wb + 28 * MB) : nullptr;  // 62.5 MiB

  // ---- one-shot weight conversion (fp32 -> bf16, fused layouts) ----
  conv_qkv_kernel<<<6144, 256, 0, stream>>>(qw, kw, vw, qkvb);
  convw_kernel<<<4096, 256, 0, stream>>>(ow, owb);
  conv_w13_kernel<<<32768, 256, 0, stream>>>(w1, w3, w13b);
  convw_kernel<<<16384, 256, 0, stream>>>(w2, w2b);
  if (bf16_logits) convw_kernel<<<32000, 256, 0, stream>>>(emb, embb);

  embed_kernel<<<BT, 256, 0, stream>>>(ids, emb, x);
  float* p0 = guf;                       // w2 split-K partials
  float* p1 = guf + (size_t)BT * DD;
  for (int l = 0; l < LL; l++) {
    rmsnorm_kernel<<<BT, 256, 0, stream>>>(x, ln1 + l * DD, hb);
    gemm_bb<0><<<dim3(QKVS / 128, BT / 128), 256, 0, stream>>>(
        hb, qkvb + (size_t)l * QKVS * DD, qkv, nullptr, BT, QKVS, DD);
    rope_kernel<<<(BT * NH * 32) / 256, 256, 0, stream>>>(qkv, NH, QKVS);
    rope_kernel<<<(BT * NKV * 32) / 256, 256, 0, stream>>>(qkv + 1024, NKV, QKVS);
    attn_fwd<<<dim3(BB * NH, TT / 64), 256, 0, stream>>>(qkv, qkv + 1024, qkv + 1280, ao);
    gemm_bb<1><<<dim3(DD / 128, BT / 128), 256, 0, stream>>>(
        ao, owb + (size_t)l * DD * DD, x, nullptr, BT, DD, DD);
    rmsnorm_kernel<<<BT, 256, 0, stream>>>(x, ln2 + l * DD, hb);
    gemm_bb<2><<<dim3((2 * ED) / 128, BT / 128), 256, 0, stream>>>(
        hb, w13b + (size_t)l * 2 * ED * DD, nullptr, hb2, BT, 2 * ED, DD);
    gemm_bb<0><<<dim3(DD / 128, BT / 128, 2), 256, 0, stream>>>(
        hb2, w2b + (size_t)l * DD * ED, p0, nullptr, BT, DD, ED);
    add2_kernel<<<(BT * DD / 4) / 256, 256, 0, stream>>>(x, p0, p1);
  }
  rmsnorm_kernel<<<BT, 256, 0, stream>>>(x, lnf, hb);
  if (bf16_logits) {
    gemm_bb<0><<<dim3(VV / 128, BT / 128), 256, 0, stream>>>(hb, embb, (float*)d_out, nullptr, BT, VV, DD);
  } else {
    gemm_bt<0><<<dim3(VV / 128, BT / 128), 256, 0, stream>>>(hb, emb, (float*)d_out, BT, VV, DD);
  }
}

// Round 3
// 1842.859 us; speedup vs baseline: 1.4821x; 1.0010x over previous
//
#include <hip/hip_runtime.h>
#include <math.h>

#define TT 1024
#define BB 2
#define DD 1024
#define NH 16
#define NKV 4
#define HD 64
#define ED 4096
#define LL 4
#define VV 32000
#define QKVS 1536   // fused qkv row stride (fp32 elements)

typedef __bf16 bf16x8 __attribute__((ext_vector_type(8)));
typedef float f32x4 __attribute__((ext_vector_type(4)));

__device__ inline unsigned short f2bf(float f) {
  unsigned u = __float_as_uint(f);
  u += 0x7fffu + ((u >> 16) & 1u);   // round-to-nearest-even
  return (unsigned short)(u >> 16);
}

#define GLL16(gsrc, ldst)                                                            \
  __builtin_amdgcn_global_load_lds((const __attribute__((address_space(1))) void*)(gsrc), \
                                   (__attribute__((address_space(3))) void*)(ldst), 16, 0, 0)

// ---------------- weight conversion: contiguous fp32 -> bf16 ----------------
__global__ void convw_kernel(const float* __restrict__ src, unsigned short* __restrict__ dst) {
  size_t i = (size_t)blockIdx.x * blockDim.x + threadIdx.x;
  float4 v = ((const float4*)src)[i];
  uint2 o;
  o.x = f2bf(v.x) | ((unsigned)f2bf(v.y) << 16);
  o.y = f2bf(v.z) | ((unsigned)f2bf(v.w) << 16);
  ((uint2*)dst)[i] = o;
}

// fused QKV weights: per layer dst [1536][1024] = [q(1024) ; k(256) ; v(256)]
__global__ void conv_qkv_kernel(const float* __restrict__ qw, const float* __restrict__ kw,
                                const float* __restrict__ vw, unsigned short* __restrict__ dst) {
  size_t i = (size_t)blockIdx.x * blockDim.x + threadIdx.x;
  size_t e = i * 4;
  int l = (int)(e / (QKVS * 1024));
  int rem = (int)(e - (size_t)l * (QKVS * 1024));
  int row = rem >> 10;
  int col = rem & 1023;
  const float* src;
  if (row < 1024) src = qw + (((size_t)l << 20) + ((size_t)row << 10)) + col;
  else if (row < 1280) src = kw + (((size_t)l << 18) + ((size_t)(row - 1024) << 10)) + col;
  else src = vw + (((size_t)l << 18) + ((size_t)(row - 1280) << 10)) + col;
  float4 v = *(const float4*)src;
  uint2 o;
  o.x = f2bf(v.x) | ((unsigned)f2bf(v.y) << 16);
  o.y = f2bf(v.z) | ((unsigned)f2bf(v.w) << 16);
  ((uint2*)dst)[i] = o;
}

// fused W1/W3, 16-row interleaved: dst row r (of 8192): grp=r>>4, f=(grp>>1)*16+(r&15);
// grp even -> w1[f], grp odd -> w3[f].  Puts gate/up for the same f-column in the same
// lane of the GEMM accumulator (frag pairs ns={0,2} offsets) -> in-register SwiGLU.
__global__ void conv_w13_kernel(const float* __restrict__ w1, const float* __restrict__ w3,
                                unsigned short* __restrict__ dst) {
  size_t i = (size_t)blockIdx.x * blockDim.x + threadIdx.x;
  size_t e = i * 4;
  int l = (int)(e >> 23);              // / (8192*1024)
  int rem = (int)(e & ((1u << 23) - 1));
  int r = rem >> 10;
  int col = rem & 1023;
  int grp = r >> 4;
  int f = (grp >> 1) * 16 + (r & 15);
  const float* base = (grp & 1) ? w3 : w1;
  const float* src = base + (((size_t)l << 22) + ((size_t)f << 10)) + col;
  float4 v = *(const float4*)src;
  uint2 o;
  o.x = f2bf(v.x) | ((unsigned)f2bf(v.y) << 16);
  o.y = f2bf(v.z) | ((unsigned)f2bf(v.w) << 16);
  ((uint2*)dst)[i] = o;
}

// ---------------- embedding gather ----------------
__global__ void embed_kernel(const int* __restrict__ ids, const float* __restrict__ emb,
                             float* __restrict__ x) {
  int row = blockIdx.x;
  int id = ids[row];
  const float4* src = (const float4*)(emb + (size_t)id * DD);
  float4* dst = (float4*)(x + (size_t)row * DD);
  dst[threadIdx.x] = src[threadIdx.x];
}

// ---------------- rmsnorm (fp32 in -> bf16 out) ----------------
__global__ __launch_bounds__(256) void rmsnorm_kernel(const float* __restrict__ x,
                                                      const float* __restrict__ wgt,
                                                      unsigned short* __restrict__ out) {
  int row = blockIdx.x;
  int tid = threadIdx.x;
  float4 v = *(const float4*)(x + (size_t)row * DD + tid * 4);
  float ss = v.x * v.x + v.y * v.y + v.z * v.z + v.w * v.w;
#pragma unroll
  for (int off = 32; off >= 1; off >>= 1) ss += __shfl_xor(ss, off);
  __shared__ float part[4];
  if ((tid & 63) == 0) part[tid >> 6] = ss;
  __syncthreads();
  ss = part[0] + part[1] + part[2] + part[3];
  float sc = rsqrtf(ss * (1.0f / DD) + 1e-6f);
  float4 wv = *(const float4*)(wgt + tid * 4);
  uint2 o;
  o.x = f2bf(v.x * wv.x * sc) | ((unsigned)f2bf(v.y * wv.y * sc) << 16);
  o.y = f2bf(v.z * wv.z * sc) | ((unsigned)f2bf(v.w * wv.w * sc) << 16);
  *(uint2*)(out + (size_t)row * DD + tid * 4) = o;
}

// ---------------- x += p0 + p1 (split-K combine + residual) ----------------
__global__ void add2_kernel(float* __restrict__ x, const float* __restrict__ p0,
                            const float* __restrict__ p1) {
  size_t i = (size_t)blockIdx.x * blockDim.x + threadIdx.x;
  float4 a = ((const float4*)x)[i];
  float4 b = ((const float4*)p0)[i];
  float4 c = ((const float4*)p1)[i];
  a.x += b.x + c.x; a.y += b.y + c.y; a.z += b.z + c.z; a.w += b.w + c.w;
  ((float4*)x)[i] = a;
}

// ---------------- GEMM (bf16 A, bf16 W): C[M,N] (+)= A[M,K] * W[N,K]^T ----------------
// m97 structure: 128x128 tile, BK=32, linear LDS, global_load_lds x16 for both operands.
// XCD swizzle on the HARDWARE dispatch id (bid = by*gx+bx, XCD = bid%8): each XCD gets a
// contiguous n-major chunk so m-tiles sharing a W panel co-reside in one XCD's L2.
// EPI 0: store fp32 (split-K: C += z*M*N)   EPI 1: accumulate into C
// EPI 2: SwiGLU -> bf16 O2                  EPI 3: RoPE (cols<1280) fp32 store (qkv)
// EPI 5: nontemporal fp32 store (logits)
template <int EPI>
__global__ __launch_bounds__(256) void gemm_bb(const unsigned short* __restrict__ A,
                                               const unsigned short* __restrict__ W,
                                               float* __restrict__ C,
                                               unsigned short* __restrict__ O2,
                                               int M, int N, int K) {
  __shared__ unsigned short As[128 * 32];
  __shared__ unsigned short Bs[128 * 32];
  const int tid = threadIdx.x;
  const int lane = tid & 63;
  const int w = tid >> 6;
  const int wm = (w >> 1) * 64;
  const int wn = (w & 1) * 64;
  const int l15 = lane & 15;
  const int quad = lane >> 4;
  const int q8 = quad * 8;

  const int nby = gridDim.y;
  const int nwg = gridDim.x * nby;
  const int bid = blockIdx.y * gridDim.x + blockIdx.x;  // hardware linear order (x fastest)
  int wk = bid;
  if ((nwg & 7) == 0) {
    int cpx = nwg >> 3;
    wk = (bid & 7) * cpx + (bid >> 3);   // XCD bid%8 -> contiguous work chunk
  }
  const int mBase = (wk % nby) * 128;    // n-major: consecutive wk share a W panel
  const int nBase = (wk / nby) * 128;

  const int ksl = K / gridDim.z;         // split-K slice (z=1 -> full K)
  const int kb0 = blockIdx.z * ksl;
  if (EPI == 0) C += (size_t)blockIdx.z * M * N;

  const unsigned short* Ab = A + (size_t)mBase * K;
  const unsigned short* Wb = W + (size_t)nBase * K;
  const int r0 = tid >> 2;            // staging row for chunk 0
  const int c8 = (tid & 3) * 8;       // staging col (elements)

  f32x4 acc[4][4] = {};

  for (int kt = kb0; kt < kb0 + ksl; kt += 32) {
    __syncthreads();
    GLL16(Ab + (size_t)r0 * K + kt + c8, As + (w * 64) * 8);
    GLL16(Ab + (size_t)(r0 + 64) * K + kt + c8, As + (256 + w * 64) * 8);
    GLL16(Wb + (size_t)r0 * K + kt + c8, Bs + (w * 64) * 8);
    GLL16(Wb + (size_t)(r0 + 64) * K + kt + c8, Bs + (256 + w * 64) * 8);
    __syncthreads();
    bf16x8 af[4], bfv[4];
#pragma unroll
    for (int ms = 0; ms < 4; ms++)
      af[ms] = *(const bf16x8*)&As[(wm + ms * 16 + l15) * 32 + q8];
#pragma unroll
    for (int ns = 0; ns < 4; ns++)
      bfv[ns] = *(const bf16x8*)&Bs[(wn + ns * 16 + l15) * 32 + q8];
#pragma unroll
    for (int ms = 0; ms < 4; ms++)
#pragma unroll
      for (int ns = 0; ns < 4; ns++)
        acc[ms][ns] = __builtin_amdgcn_mfma_f32_16x16x32_bf16(af[ms], bfv[ns], acc[ms][ns], 0, 0, 0);
  }

  if (EPI == 2) {
    // interleaved gate/up: frag ns even = gate, ns odd = up, same f in same lane
    const int fBase = ((nBase + wn) >> 5) * 16;
#pragma unroll
    for (int ms = 0; ms < 4; ms++)
#pragma unroll
      for (int r = 0; r < 4; r++) {
        int row = mBase + wm + ms * 16 + quad * 4 + r;
#pragma unroll
        for (int pp = 0; pp < 2; pp++) {
          float g = acc[ms][pp * 2][r];
          float u = acc[ms][pp * 2 + 1][r];
          float res = g / (1.f + __expf(-g)) * u;
          O2[(size_t)row * ED + fBase + pp * 16 + l15] = f2bf(res);
        }
      }
  } else if (EPI == 3) {
    // qkv output with fused RoPE. Pair (d, d+32) = frags (ns, ns+2), same lane.
    const bool dorope = (nBase < 1280);  // q: 0..1023, k: 1024..1279, v: plain
#pragma unroll
    for (int ms = 0; ms < 4; ms++)
#pragma unroll
      for (int r = 0; r < 4; r++) {
        int row = mBase + wm + ms * 16 + quad * 4 + r;
        float pos = (float)(row & (TT - 1));
#pragma unroll
        for (int ns = 0; ns < 2; ns++) {
          int col = nBase + wn + ns * 16 + l15;
          size_t i1 = (size_t)row * N + col;
          float x1 = acc[ms][ns][r], x2 = acc[ms][ns + 2][r];
          if (dorope) {
            int j = ns * 16 + l15;   // head-dim pair index 0..31
            float invf = __expf(-(float)j * 0.28782313662f);  // 10000^(-j/32)
            float sv, cv;
            sincosf(pos * invf, &sv, &cv);
            C[i1] = x1 * cv - x2 * sv;
            C[i1 + 32] = x2 * cv + x1 * sv;
          } else {
            C[i1] = x1;
            C[i1 + 32] = x2;
          }
        }
      }
  } else {
#pragma unroll
    for (int ms = 0; ms < 4; ms++)
#pragma unroll
      for (int ns = 0; ns < 4; ns++)
#pragma unroll
        for (int r = 0; r < 4; r++) {
          int row = mBase + wm + ms * 16 + quad * 4 + r;
          int col = nBase + wn + ns * 16 + l15;
          size_t idx = (size_t)row * N + col;
          if (EPI == 0) C[idx] = acc[ms][ns][r];
          else if (EPI == 5) __builtin_nontemporal_store(acc[ms][ns][r], &C[idx]);
          else C[idx] += acc[ms][ns][r];
        }
  }
}

// ---------------- GEMM fallback: bf16 A * fp32 W (converted in staging) ----------------
template <int EPI>
__global__ __launch_bounds__(256) void gemm_bt(const unsigned short* __restrict__ A,
                                               const float* __restrict__ W,
                                               float* __restrict__ C, int M, int N, int K) {
  __shared__ unsigned short As[128 * 40];
  __shared__ unsigned short Bs[128 * 40];
  const int tid = threadIdx.x;
  const int lane = tid & 63;
  const int w = tid >> 6;
  const int wm = (w >> 1) * 64;
  const int wn = (w & 1) * 64;
  const int l15 = lane & 15;
  const int quad = lane >> 4;
  const int q8 = quad * 8;

  const int nby = gridDim.y;
  const int nwg = gridDim.x * nby;
  const int bid = blockIdx.y * gridDim.x + blockIdx.x;
  int wk = bid;
  if ((nwg & 7) == 0) {
    int cpx = nwg >> 3;
    wk = (bid & 7) * cpx + (bid >> 3);
  }
  const int mBase = (wk % nby) * 128;
  const int nBase = (wk / nby) * 128;

  f32x4 acc[4][4] = {};

  for (int kt = 0; kt < K; kt += 32) {
    __syncthreads();
#pragma unroll
    for (int i = 0; i < 2; i++) {
      int chunk = tid + 256 * i;
      int r = chunk >> 2, cc8 = (chunk & 3) * 8;
      uint4 v = *(const uint4*)(A + (size_t)(mBase + r) * K + kt + cc8);
      *(uint4*)&As[r * 40 + cc8] = v;
    }
#pragma unroll
    for (int i = 0; i < 2; i++) {
      int chunk = tid + 256 * i;
      int r = chunk >> 2, cc8 = (chunk & 3) * 8;
      const float4* wp = (const float4*)(W + (size_t)(nBase + r) * K + kt + cc8);
      float4 f0 = wp[0], f1 = wp[1];
      uint4 v;
      v.x = f2bf(f0.x) | ((unsigned)f2bf(f0.y) << 16);
      v.y = f2bf(f0.z) | ((unsigned)f2bf(f0.w) << 16);
      v.z = f2bf(f1.x) | ((unsigned)f2bf(f1.y) << 16);
      v.w = f2bf(f1.z) | ((unsigned)f2bf(f1.w) << 16);
      *(uint4*)&Bs[r * 40 + cc8] = v;
    }
    __syncthreads();
    bf16x8 af[4], bfv[4];
#pragma unroll
    for (int ms = 0; ms < 4; ms++)
      af[ms] = *(const bf16x8*)&As[(wm + ms * 16 + l15) * 40 + q8];
#pragma unroll
    for (int ns = 0; ns < 4; ns++)
      bfv[ns] = *(const bf16x8*)&Bs[(wn + ns * 16 + l15) * 40 + q8];
#pragma unroll
    for (int ms = 0; ms < 4; ms++)
#pragma unroll
      for (int ns = 0; ns < 4; ns++)
        acc[ms][ns] = __builtin_amdgcn_mfma_f32_16x16x32_bf16(af[ms], bfv[ns], acc[ms][ns], 0, 0, 0);
  }
#pragma unroll
  for (int ms = 0; ms < 4; ms++)
#pragma unroll
    for (int ns = 0; ns < 4; ns++)
#pragma unroll
      for (int r = 0; r < 4; r++) {
        int row = mBase + wm + ms * 16 + quad * 4 + r;
        int col = nBase + wn + ns * 16 + l15;
        size_t idx = (size_t)row * N + col;
        if (EPI == 0) C[idx] = acc[ms][ns][r];
        else C[idx] += acc[ms][ns][r];
      }
}

// ---------------- flash attention (bf16 MFMA, fp32 softmax) ----------------
__global__ __launch_bounds__(256) void attn_fwd(const float* __restrict__ Q,
                                                const float* __restrict__ Kb,
                                                const float* __restrict__ Vb,
                                                unsigned short* __restrict__ O) {
  __shared__ unsigned short Qs[64 * 72];  // reused as P after Q frags are in regs
  __shared__ unsigned short Ks[64 * 72];
  __shared__ unsigned short Vt[64 * 72];  // transposed V: [d][key]
  const int tid = threadIdx.x;
  const int lane = tid & 63;
  const int w = tid >> 6;
  const int l15 = lane & 15;
  const int quad = lane >> 4;
  const int q8 = quad * 8;
  const int bh = blockIdx.x;
  const int b = bh / NH, h = bh % NH;
  const int hkv = h >> 2;
  const int qb = blockIdx.y;

#pragma unroll
  for (int i = 0; i < 4; i++) {  // stage Q tile 64x64
    int cc = tid + 256 * i;
    int r = cc >> 4, d4 = (cc & 15) * 4;
    float4 v = *(const float4*)(Q + (size_t)(b * TT + qb * 64 + r) * QKVS + h * HD + d4);
    uint2 p;
    p.x = f2bf(v.x) | ((unsigned)f2bf(v.y) << 16);
    p.y = f2bf(v.z) | ((unsigned)f2bf(v.w) << 16);
    *(uint2*)&Qs[r * 72 + d4] = p;
  }
  __syncthreads();
  bf16x8 qa0 = *(const bf16x8*)&Qs[(w * 16 + l15) * 72 + q8];
  bf16x8 qa1 = *(const bf16x8*)&Qs[(w * 16 + l15) * 72 + 32 + q8];

  f32x4 oacc[4] = {};
  float m_i[4], l_i[4];
#pragma unroll
  for (int r = 0; r < 4; r++) { m_i[r] = -1e30f; l_i[r] = 0.f; }

  for (int kb = 0; kb <= qb; kb++) {
    __syncthreads();
#pragma unroll
    for (int i = 0; i < 4; i++) {  // stage K (row-major) and V (transposed)
      int cc = tid + 256 * i;
      int r = cc >> 4, d4 = (cc & 15) * 4;
      size_t grow = (size_t)(b * TT + kb * 64 + r) * QKVS + hkv * HD + d4;
      float4 kv = *(const float4*)(Kb + grow);
      uint2 p;
      p.x = f2bf(kv.x) | ((unsigned)f2bf(kv.y) << 16);
      p.y = f2bf(kv.z) | ((unsigned)f2bf(kv.w) << 16);
      *(uint2*)&Ks[r * 72 + d4] = p;
      float4 vv = *(const float4*)(Vb + grow);
      Vt[(d4 + 0) * 72 + r] = f2bf(vv.x);
      Vt[(d4 + 1) * 72 + r] = f2bf(vv.y);
      Vt[(d4 + 2) * 72 + r] = f2bf(vv.z);
      Vt[(d4 + 3) * 72 + r] = f2bf(vv.w);
    }
    __syncthreads();
    // S = Q K^T : 16 q-rows x 64 keys per wave
    f32x4 s[4];
#pragma unroll
    for (int ns = 0; ns < 4; ns++) {
      bf16x8 k0 = *(const bf16x8*)&Ks[(ns * 16 + l15) * 72 + q8];
      bf16x8 k1 = *(const bf16x8*)&Ks[(ns * 16 + l15) * 72 + 32 + q8];
      f32x4 z = {};
      z = __builtin_amdgcn_mfma_f32_16x16x32_bf16(qa0, k0, z, 0, 0, 0);
      s[ns] = __builtin_amdgcn_mfma_f32_16x16x32_bf16(qa1, k1, z, 0, 0, 0);
    }
#pragma unroll
    for (int ns = 0; ns < 4; ns++)
#pragma unroll
      for (int r = 0; r < 4; r++) {
        float sv = s[ns][r] * 0.125f;  // 1/sqrt(64)
        if (kb == qb) {
          int qloc = w * 16 + quad * 4 + r;
          int kloc = ns * 16 + l15;
          if (kloc > qloc) sv = -1e30f;
        }
        s[ns][r] = sv;
      }
    // online softmax; row r lives in the 16-lane group (quad fixed)
    float p[4][4];
    float alpha[4];
#pragma unroll
    for (int r = 0; r < 4; r++) {
      float mx = fmaxf(fmaxf(s[0][r], s[1][r]), fmaxf(s[2][r], s[3][r]));
#pragma unroll
      for (int off = 1; off < 16; off <<= 1) mx = fmaxf(mx, __shfl_xor(mx, off));
      float mnew = fmaxf(m_i[r], mx);
      alpha[r] = __expf(m_i[r] - mnew);
      float rs = 0.f;
#pragma unroll
      for (int ns = 0; ns < 4; ns++) {
        p[ns][r] = __expf(s[ns][r] - mnew);
        rs += p[ns][r];
      }
#pragma unroll
      for (int off = 1; off < 16; off <<= 1) rs += __shfl_xor(rs, off);
      l_i[r] = l_i[r] * alpha[r] + rs;
      m_i[r] = mnew;
    }
#pragma unroll
    for (int ds = 0; ds < 4; ds++)
#pragma unroll
      for (int r = 0; r < 4; r++) oacc[ds][r] *= alpha[r];
    // P: C-layout regs -> LDS (A-layout read). Per-wave private 16-row strip.
#pragma unroll
    for (int ns = 0; ns < 4; ns++)
#pragma unroll
      for (int r = 0; r < 4; r++)
        Qs[(w * 16 + quad * 4 + r) * 72 + ns * 16 + l15] = f2bf(p[ns][r]);
    __syncthreads();
    bf16x8 pa0 = *(const bf16x8*)&Qs[(w * 16 + l15) * 72 + q8];
    bf16x8 pa1 = *(const bf16x8*)&Qs[(w * 16 + l15) * 72 + 32 + q8];
#pragma unroll
    for (int ds = 0; ds < 4; ds++) {
      bf16x8 v0 = *(const bf16x8*)&Vt[(ds * 16 + l15) * 72 + q8];
      bf16x8 v1 = *(const bf16x8*)&Vt[(ds * 16 + l15) * 72 + 32 + q8];
      oacc[ds] = __builtin_amdgcn_mfma_f32_16x16x32_bf16(pa0, v0, oacc[ds], 0, 0, 0);
      oacc[ds] = __builtin_amdgcn_mfma_f32_16x16x32_bf16(pa1, v1, oacc[ds], 0, 0, 0);
    }
  }
#pragma unroll
  for (int ds = 0; ds < 4; ds++)
#pragma unroll
    for (int r = 0; r < 4; r++) {
      int row = qb * 64 + w * 16 + quad * 4 + r;
      int col = h * HD + ds * 16 + l15;
      O[(size_t)(b * TT + row) * DD + col] = f2bf(oacc[ds][r] / l_i[r]);
    }
}

extern "C" void kernel_launch(void* const* d_in, const int* in_sizes, int n_in,
                              void* d_out, int out_size, void* d_ws, size_t ws_size,
                              hipStream_t stream) {
  const int* ids = (const int*)d_in[0];
  const float* emb = (const float*)d_in[1];
  const float* ln1 = (const float*)d_in[2];
  const float* qw = (const float*)d_in[3];
  const float* kw = (const float*)d_in[4];
  const float* vw = (const float*)d_in[5];
  const float* ow = (const float*)d_in[6];
  const float* ln2 = (const float*)d_in[7];
  const float* w1 = (const float*)d_in[8];
  const float* w2 = (const float*)d_in[9];
  const float* w3 = (const float*)d_in[10];
  const float* lnf = (const float*)d_in[11];

  const int BT = BB * TT;  // 2048
  const size_t MB = 1024ull * 1024ull;
  char* ob = (char*)d_out;  // 250 MiB; logits written only at the very end

  // d_out scratch layout (all dead before the logits GEMM writes d_out):
  float* guf = (float*)ob;                                   // 64 MiB  (w2 split-K partials)
  unsigned short* hb2 = (unsigned short*)(ob + 64 * MB);     // 16 MiB  [2048][4096] bf16
  unsigned short* qkvb = (unsigned short*)(ob + 80 * MB);    // 12 MiB  L x [1536][1024] bf16
  unsigned short* owb = (unsigned short*)(ob + 92 * MB);     //  8 MiB  L x [1024][1024] bf16
  unsigned short* w13b = (unsigned short*)(ob + 100 * MB);   // 64 MiB  L x [8192][1024] bf16
  unsigned short* w2b = (unsigned short*)(ob + 164 * MB);    // 32 MiB  L x [1024][4096] bf16
  // ends at 196 MiB; 196..250 free for fallback activations

  char* wb = (char*)d_ws;
  unsigned short* hb = (unsigned short*)wb;  // 4 MiB (ws must be >= 4 MiB)
  float* x;
  float* qkv;
  unsigned short* ao;
  if (ws_size >= 28 * MB) {
    x = (float*)(wb + 4 * MB);              // 8 MiB
    qkv = (float*)(wb + 12 * MB);           // 12 MiB [2048][1536] fp32
    ao = (unsigned short*)(wb + 24 * MB);   // 4 MiB
  } else {
    x = (float*)(ob + 196 * MB);
    qkv = (float*)(ob + 204 * MB);
    ao = (unsigned short*)(ob + 216 * MB);
  }
  const bool bf16_logits = (ws_size >= 92 * MB);
  unsigned short* embb = bf16_logits ? (unsigned short*)(wb + 28 * MB) : nullptr;  // 62.5 MiB

  // ---- one-shot weight conversion (fp32 -> bf16, fused layouts) ----
  conv_qkv_kernel<<<6144, 256, 0, stream>>>(qw, kw, vw, qkvb);
  convw_kernel<<<4096, 256, 0, stream>>>(ow, owb);
  conv_w13_kernel<<<32768, 256, 0, stream>>>(w1, w3, w13b);
  convw_kernel<<<16384, 256, 0, stream>>>(w2, w2b);
  if (bf16_logits) convw_kernel<<<32000, 256, 0, stream>>>(emb, embb);

  embed_kernel<<<BT, 256, 0, stream>>>(ids, emb, x);
  float* p0 = guf;                       // w2 split-K partials
  float* p1 = guf + (size_t)BT * DD;
  for (int l = 0; l < LL; l++) {
    rmsnorm_kernel<<<BT, 256, 0, stream>>>(x, ln1 + l * DD, hb);
    gemm_bb<3><<<dim3(QKVS / 128, BT / 128), 256, 0, stream>>>(
        hb, qkvb + (size_t)l * QKVS * DD, qkv, nullptr, BT, QKVS, DD);
    attn_fwd<<<dim3(BB * NH, TT / 64), 256, 0, stream>>>(qkv, qkv + 1024, qkv + 1280, ao);
    gemm_bb<1><<<dim3(DD / 128, BT / 128), 256, 0, stream>>>(
        ao, owb + (size_t)l * DD * DD, x, nullptr, BT, DD, DD);
    rmsnorm_kernel<<<BT, 256, 0, stream>>>(x, ln2 + l * DD, hb);
    gemm_bb<2><<<dim3((2 * ED) / 128, BT / 128), 256, 0, stream>>>(
        hb, w13b + (size_t)l * 2 * ED * DD, nullptr, hb2, BT, 2 * ED, DD);
    gemm_bb<0><<<dim3(DD / 128, BT / 128, 2), 256, 0, stream>>>(
        hb2, w2b + (size_t)l * DD * ED, p0, nullptr, BT, DD, ED);
    add2_kernel<<<(BT * DD / 4) / 256, 256, 0, stream>>>(x, p0, p1);
  }
  rmsnorm_kernel<<<BT, 256, 0, stream>>>(x, lnf, hb);
  if (bf16_logits) {
    gemm_bb<5><<<dim3(VV / 128, BT / 128), 256, 0, stream>>>(hb, embb, (float*)d_out, nullptr, BT, VV, DD);
  } else {
    gemm_bt<0><<<dim3(VV / 128, BT / 128), 256, 0, stream>>>(hb, emb, (float*)d_out, BT, VV, DD);
  }
}

// Round 4
// 1752.737 us; speedup vs baseline: 1.5583x; 1.0514x over previous
//
#include <hip/hip_runtime.h>
#include <math.h>

#define TT 1024
#define BB 2
#define DD 1024
#define NH 16
#define NKV 4
#define HD 64
#define ED 4096
#define LL 4
#define VV 32000
#define QKVS 1536   // fused qkv row stride (fp32 elements)

typedef __bf16 bf16x8 __attribute__((ext_vector_type(8)));
typedef float f32x4 __attribute__((ext_vector_type(4)));

__device__ inline unsigned short f2bf(float f) {
  unsigned u = __float_as_uint(f);
  u += 0x7fffu + ((u >> 16) & 1u);   // round-to-nearest-even
  return (unsigned short)(u >> 16);
}

#define GLL16(gsrc, ldst)                                                            \
  __builtin_amdgcn_global_load_lds((const __attribute__((address_space(1))) void*)(gsrc), \
                                   (__attribute__((address_space(3))) void*)(ldst), 16, 0, 0)

// ---------------- weight conversion: contiguous fp32 -> bf16 ----------------
__global__ void convw_kernel(const float* __restrict__ src, unsigned short* __restrict__ dst) {
  size_t i = (size_t)blockIdx.x * blockDim.x + threadIdx.x;
  float4 v = ((const float4*)src)[i];
  uint2 o;
  o.x = f2bf(v.x) | ((unsigned)f2bf(v.y) << 16);
  o.y = f2bf(v.z) | ((unsigned)f2bf(v.w) << 16);
  ((uint2*)dst)[i] = o;
}

// fused QKV weights: per layer dst [1536][1024] = [q(1024) ; k(256) ; v(256)]
__global__ void conv_qkv_kernel(const float* __restrict__ qw, const float* __restrict__ kw,
                                const float* __restrict__ vw, unsigned short* __restrict__ dst) {
  size_t i = (size_t)blockIdx.x * blockDim.x + threadIdx.x;
  size_t e = i * 4;
  int l = (int)(e / (QKVS * 1024));
  int rem = (int)(e - (size_t)l * (QKVS * 1024));
  int row = rem >> 10;
  int col = rem & 1023;
  const float* src;
  if (row < 1024) src = qw + (((size_t)l << 20) + ((size_t)row << 10)) + col;
  else if (row < 1280) src = kw + (((size_t)l << 18) + ((size_t)(row - 1024) << 10)) + col;
  else src = vw + (((size_t)l << 18) + ((size_t)(row - 1280) << 10)) + col;
  float4 v = *(const float4*)src;
  uint2 o;
  o.x = f2bf(v.x) | ((unsigned)f2bf(v.y) << 16);
  o.y = f2bf(v.z) | ((unsigned)f2bf(v.w) << 16);
  ((uint2*)dst)[i] = o;
}

// fused W1/W3, 16-row interleaved: dst row r: grp=r>>4, f=(grp>>1)*16+(r&15);
// grp even -> w1[f], grp odd -> w3[f].
__global__ void conv_w13_kernel(const float* __restrict__ w1, const float* __restrict__ w3,
                                unsigned short* __restrict__ dst) {
  size_t i = (size_t)blockIdx.x * blockDim.x + threadIdx.x;
  size_t e = i * 4;
  int l = (int)(e >> 23);
  int rem = (int)(e & ((1u << 23) - 1));
  int r = rem >> 10;
  int col = rem & 1023;
  int grp = r >> 4;
  int f = (grp >> 1) * 16 + (r & 15);
  const float* base = (grp & 1) ? w3 : w1;
  const float* src = base + (((size_t)l << 22) + ((size_t)f << 10)) + col;
  float4 v = *(const float4*)src;
  uint2 o;
  o.x = f2bf(v.x) | ((unsigned)f2bf(v.y) << 16);
  o.y = f2bf(v.z) | ((unsigned)f2bf(v.w) << 16);
  ((uint2*)dst)[i] = o;
}

// ---------------- embedding gather ----------------
__global__ void embed_kernel(const int* __restrict__ ids, const float* __restrict__ emb,
                             float* __restrict__ x) {
  int row = blockIdx.x;
  int id = ids[row];
  const float4* src = (const float4*)(emb + (size_t)id * DD);
  float4* dst = (float4*)(x + (size_t)row * DD);
  dst[threadIdx.x] = src[threadIdx.x];
}

// ---------------- rmsnorm (fp32 in -> bf16 out) ----------------
__global__ __launch_bounds__(256) void rmsnorm_kernel(const float* __restrict__ x,
                                                      const float* __restrict__ wgt,
                                                      unsigned short* __restrict__ out) {
  int row = blockIdx.x;
  int tid = threadIdx.x;
  float4 v = *(const float4*)(x + (size_t)row * DD + tid * 4);
  float ss = v.x * v.x + v.y * v.y + v.z * v.z + v.w * v.w;
#pragma unroll
  for (int off = 32; off >= 1; off >>= 1) ss += __shfl_xor(ss, off);
  __shared__ float part[4];
  if ((tid & 63) == 0) part[tid >> 6] = ss;
  __syncthreads();
  ss = part[0] + part[1] + part[2] + part[3];
  float sc = rsqrtf(ss * (1.0f / DD) + 1e-6f);
  float4 wv = *(const float4*)(wgt + tid * 4);
  uint2 o;
  o.x = f2bf(v.x * wv.x * sc) | ((unsigned)f2bf(v.y * wv.y * sc) << 16);
  o.y = f2bf(v.z * wv.z * sc) | ((unsigned)f2bf(v.w * wv.w * sc) << 16);
  *(uint2*)(out + (size_t)row * DD + tid * 4) = o;
}

// ---------------- x += p0 + p1 (split-K combine + residual) ----------------
__global__ void add2_kernel(float* __restrict__ x, const float* __restrict__ p0,
                            const float* __restrict__ p1) {
  size_t i = (size_t)blockIdx.x * blockDim.x + threadIdx.x;
  float4 a = ((const float4*)x)[i];
  float4 b = ((const float4*)p0)[i];
  float4 c = ((const float4*)p1)[i];
  a.x += b.x + c.x; a.y += b.y + c.y; a.z += b.z + c.z; a.w += b.w + c.w;
  ((float4*)x)[i] = a;
}

// ================= 256x256 8-phase GEMM (T2 swizzle + T3/T4 counted vmcnt + T5) =======
// C[M,N] = A[M,K](bf16) * W[N,K]^T(bf16).  512 threads, 8 waves (2M x 4N), BK=64.
// LDS: per operand a 3-slot ring of K-half planes [256 rows][32 cols] (16KB each) ->
// 96KB total. Main-loop waits are vmcnt(4) (3 half-planes in flight), never 0.
// Swizzle (rule #21, both-sides): linear gld dest + permuted global source
// (gg = (l&3)^((l>>2)&3)) + same XOR on ds_read (quad^(l15&3)) -> balanced banks.
// EPI 5: nontemporal fp32 store (logits).  EPI 2: SwiGLU -> bf16 O2 (w13).
template <int EPI>
__global__ __launch_bounds__(512) void gemm_8p(const unsigned short* __restrict__ A,
                                               const unsigned short* __restrict__ W,
                                               float* __restrict__ C,
                                               unsigned short* __restrict__ O2,
                                               int M, int N, int K) {
  __shared__ unsigned short lds[49152];  // A planes: slot*8192; B planes: 24576 + slot*8192
  const int tid = threadIdx.x;
  const int lane = tid & 63;
  const int w = tid >> 6;
  const int wr = w >> 2;    // 0..1  M-half of wave
  const int wc = w & 3;     // 0..3  N-quarter of wave
  const int l15 = lane & 15;
  const int quad = lane >> 4;
  const int rq = ((quad ^ (l15 & 3)) << 3);                  // swizzled group (read side)
  const int glr = lane >> 2;                                  // gld row-in-16
  const int gg8 = (((lane & 3) ^ ((lane >> 2) & 3)) << 3);    // gld col perm (write side)

  const int nby = gridDim.y;
  const int nwg = gridDim.x * nby;
  const int bid = blockIdx.y * gridDim.x + blockIdx.x;        // hw linear (x fastest)
  int wk = bid;
  if ((nwg & 7) == 0) { int cpx = nwg >> 3; wk = (bid & 7) * cpx + (bid >> 3); }
  const int mBase = (wk % nby) * 256;
  const int nBase = (wk / nby) * 256;

  // per-thread global source bases (element units); +KOFF per staged half
  const unsigned short* gA0 = A + (size_t)(mBase + w * 16 + glr) * K + gg8;
  const unsigned short* gA1 = A + (size_t)(mBase + 128 + w * 16 + glr) * K + gg8;
  const unsigned short* gB0 = W + (size_t)(nBase + w * 16 + glr) * K + gg8;
  const unsigned short* gB1 = W + (size_t)(nBase + 128 + w * 16 + glr) * K + gg8;

#define STGA(SLOT, KOFF) do { \
    GLL16(gA0 + (KOFF), &lds[(SLOT) * 8192 + w * 512]); \
    GLL16(gA1 + (KOFF), &lds[(SLOT) * 8192 + 4096 + w * 512]); } while (0)
#define STGB(SLOT, KOFF) do { \
    GLL16(gB0 + (KOFF), &lds[24576 + (SLOT) * 8192 + w * 512]); \
    GLL16(gB1 + (KOFF), &lds[24576 + (SLOT) * 8192 + 4096 + w * 512]); } while (0)
#define LDA_(OFF, MH, MI) (*(const bf16x8*)&lds[(OFF) + (wr * 128 + (MH) * 64 + (MI) * 16 + l15) * 32 + rq])
#define LDB_(OFF, NF)     (*(const bf16x8*)&lds[24576 + (OFF) + (wc * 64 + (NF) * 16 + l15) * 32 + rq])
#define MM(MF, NF, AR, BR) acc[MF][NF] = __builtin_amdgcn_mfma_f32_16x16x32_bf16(AR, BR, acc[MF][NF], 0, 0, 0)
#define MFMA16(MH) do { \
    MM((MH)*4+0, 0, a0, b0); MM((MH)*4+0, 1, a0, b1); MM((MH)*4+0, 2, a0, b2); MM((MH)*4+0, 3, a0, b3); \
    MM((MH)*4+1, 0, a1, b0); MM((MH)*4+1, 1, a1, b1); MM((MH)*4+1, 2, a1, b2); MM((MH)*4+1, 3, a1, b3); \
    MM((MH)*4+2, 0, a2, b0); MM((MH)*4+2, 1, a2, b1); MM((MH)*4+2, 2, a2, b2); MM((MH)*4+2, 3, a2, b3); \
    MM((MH)*4+3, 0, a3, b0); MM((MH)*4+3, 1, a3, b1); MM((MH)*4+3, 2, a3, b2); MM((MH)*4+3, 3, a3, b3); } while (0)
#define CFENCE asm volatile("" ::: "memory")

  f32x4 acc[8][4] = {};
  int s0 = 0, s1 = 1;  // ring slots holding current tile's ks0 / ks1 halves

  // prologue: stage tile0 (ks0 -> slot0, ks1 -> slot1)
  STGA(0, 0); STGB(0, 0);
  STGA(1, 32); STGB(1, 32);
  CFENCE;
  asm volatile("s_waitcnt vmcnt(4)" ::: "memory");  // ks0(0) landed; ks1(0) in flight
  __builtin_amdgcn_s_barrier();

  const int NT = K >> 6;
  for (int t = 0; t < NT; ++t) {
    const bool last = (t == NT - 1);
    const int sn = 3 - s0 - s1;          // free slot -> ks0(t+1)
    const int ktn = (t + 1) << 6;
    const int aoff0 = s0 * 8192, aoff1 = s1 * 8192;
    bf16x8 a0, a1, a2, a3, b0, b1, b2, b3;

    // ---- P1: (mh=0, ks=0); stage ks0(t+1) -> sn ----
    a0 = LDA_(aoff0, 0, 0); a1 = LDA_(aoff0, 0, 1); a2 = LDA_(aoff0, 0, 2); a3 = LDA_(aoff0, 0, 3);
    b0 = LDB_(aoff0, 0); b1 = LDB_(aoff0, 1); b2 = LDB_(aoff0, 2); b3 = LDB_(aoff0, 3);
    if (!last) { STGA(sn, ktn); STGB(sn, ktn); }
    CFENCE;
    __builtin_amdgcn_s_barrier();
    __builtin_amdgcn_sched_barrier(0);
    __builtin_amdgcn_s_setprio(1);
    MFMA16(0);
    __builtin_amdgcn_s_setprio(0);
    CFENCE;
    __builtin_amdgcn_s_barrier();

    // ---- P2: (mh=1, ks=0); b regs reused; guard ks1(t) ----
    a0 = LDA_(aoff0, 1, 0); a1 = LDA_(aoff0, 1, 1); a2 = LDA_(aoff0, 1, 2); a3 = LDA_(aoff0, 1, 3);
    CFENCE;
    __builtin_amdgcn_s_barrier();
    __builtin_amdgcn_sched_barrier(0);
    __builtin_amdgcn_s_setprio(1);
    MFMA16(1);
    __builtin_amdgcn_s_setprio(0);
    if (last) { asm volatile("s_waitcnt vmcnt(0)" ::: "memory"); }
    else      { asm volatile("s_waitcnt vmcnt(4)" ::: "memory"); }
    CFENCE;
    __builtin_amdgcn_s_barrier();

    // ---- P3: (mh=0, ks=1); stage ks1(t+1) -> s0 (its last read was P2) ----
    a0 = LDA_(aoff1, 0, 0); a1 = LDA_(aoff1, 0, 1); a2 = LDA_(aoff1, 0, 2); a3 = LDA_(aoff1, 0, 3);
    b0 = LDB_(aoff1, 0); b1 = LDB_(aoff1, 1); b2 = LDB_(aoff1, 2); b3 = LDB_(aoff1, 3);
    if (!last) { STGA(s0, ktn + 32); STGB(s0, ktn + 32); }
    CFENCE;
    __builtin_amdgcn_s_barrier();
    __builtin_amdgcn_sched_barrier(0);
    __builtin_amdgcn_s_setprio(1);
    MFMA16(0);
    __builtin_amdgcn_s_setprio(0);
    CFENCE;
    __builtin_amdgcn_s_barrier();

    // ---- P4: (mh=1, ks=1); guard ks0(t+1) for next P1 ----
    a0 = LDA_(aoff1, 1, 0); a1 = LDA_(aoff1, 1, 1); a2 = LDA_(aoff1, 1, 2); a3 = LDA_(aoff1, 1, 3);
    CFENCE;
    __builtin_amdgcn_s_barrier();
    __builtin_amdgcn_sched_barrier(0);
    __builtin_amdgcn_s_setprio(1);
    MFMA16(1);
    __builtin_amdgcn_s_setprio(0);
    if (!last) { asm volatile("s_waitcnt vmcnt(4)" ::: "memory"); }
    CFENCE;
    __builtin_amdgcn_s_barrier();

    s1 = s0; s0 = sn;  // rotate ring: next tile ks0=sn, ks1=old s0
  }

  // -------- epilogue --------
  if (EPI == 2) {
    const int fBase = ((nBase + wc * 64) >> 5) * 16;
#pragma unroll
    for (int mf = 0; mf < 8; mf++)
#pragma unroll
      for (int rr = 0; rr < 4; rr++) {
        int row = mBase + wr * 128 + mf * 16 + quad * 4 + rr;
#pragma unroll
        for (int pp = 0; pp < 2; pp++) {
          float g = acc[mf][pp * 2][rr];
          float u = acc[mf][pp * 2 + 1][rr];
          float res = g / (1.f + __expf(-g)) * u;
          O2[(size_t)row * ED + fBase + pp * 16 + l15] = f2bf(res);
        }
      }
  } else {
#pragma unroll
    for (int mf = 0; mf < 8; mf++)
#pragma unroll
      for (int nf = 0; nf < 4; nf++)
#pragma unroll
        for (int rr = 0; rr < 4; rr++) {
          int row = mBase + wr * 128 + mf * 16 + quad * 4 + rr;
          int col = nBase + wc * 64 + nf * 16 + l15;
          __builtin_nontemporal_store(acc[mf][nf][rr], &C[(size_t)row * N + col]);
        }
  }
#undef STGA
#undef STGB
#undef LDA_
#undef LDB_
#undef MM
#undef MFMA16
#undef CFENCE
}

// ---------------- 128x128 GEMM (bf16 A, bf16 W), m97 structure ----------------
// EPI 0: store fp32 (split-K: C += z*M*N)   EPI 1: accumulate into C
// EPI 3: RoPE (cols<1280) fp32 store (qkv)
template <int EPI>
__global__ __launch_bounds__(256) void gemm_bb(const unsigned short* __restrict__ A,
                                               const unsigned short* __restrict__ W,
                                               float* __restrict__ C,
                                               unsigned short* __restrict__ O2,
                                               int M, int N, int K) {
  __shared__ unsigned short As[128 * 32];
  __shared__ unsigned short Bs[128 * 32];
  const int tid = threadIdx.x;
  const int lane = tid & 63;
  const int w = tid >> 6;
  const int wm = (w >> 1) * 64;
  const int wn = (w & 1) * 64;
  const int l15 = lane & 15;
  const int quad = lane >> 4;
  const int q8 = quad * 8;

  const int nby = gridDim.y;
  const int nwg = gridDim.x * nby;
  const int bid = blockIdx.y * gridDim.x + blockIdx.x;
  int wk = bid;
  if ((nwg & 7) == 0) {
    int cpx = nwg >> 3;
    wk = (bid & 7) * cpx + (bid >> 3);
  }
  const int mBase = (wk % nby) * 128;
  const int nBase = (wk / nby) * 128;

  const int ksl = K / gridDim.z;
  const int kb0 = blockIdx.z * ksl;
  if (EPI == 0) C += (size_t)blockIdx.z * M * N;

  const unsigned short* Ab = A + (size_t)mBase * K;
  const unsigned short* Wb = W + (size_t)nBase * K;
  const int r0 = tid >> 2;
  const int c8 = (tid & 3) * 8;

  f32x4 acc[4][4] = {};

  for (int kt = kb0; kt < kb0 + ksl; kt += 32) {
    __syncthreads();
    GLL16(Ab + (size_t)r0 * K + kt + c8, As + (w * 64) * 8);
    GLL16(Ab + (size_t)(r0 + 64) * K + kt + c8, As + (256 + w * 64) * 8);
    GLL16(Wb + (size_t)r0 * K + kt + c8, Bs + (w * 64) * 8);
    GLL16(Wb + (size_t)(r0 + 64) * K + kt + c8, Bs + (256 + w * 64) * 8);
    __syncthreads();
    bf16x8 af[4], bfv[4];
#pragma unroll
    for (int ms = 0; ms < 4; ms++)
      af[ms] = *(const bf16x8*)&As[(wm + ms * 16 + l15) * 32 + q8];
#pragma unroll
    for (int ns = 0; ns < 4; ns++)
      bfv[ns] = *(const bf16x8*)&Bs[(wn + ns * 16 + l15) * 32 + q8];
#pragma unroll
    for (int ms = 0; ms < 4; ms++)
#pragma unroll
      for (int ns = 0; ns < 4; ns++)
        acc[ms][ns] = __builtin_amdgcn_mfma_f32_16x16x32_bf16(af[ms], bfv[ns], acc[ms][ns], 0, 0, 0);
  }

  if (EPI == 3) {
    const bool dorope = (nBase < 1280);
#pragma unroll
    for (int ms = 0; ms < 4; ms++)
#pragma unroll
      for (int r = 0; r < 4; r++) {
        int row = mBase + wm + ms * 16 + quad * 4 + r;
        float pos = (float)(row & (TT - 1));
#pragma unroll
        for (int ns = 0; ns < 2; ns++) {
          int col = nBase + wn + ns * 16 + l15;
          size_t i1 = (size_t)row * N + col;
          float x1 = acc[ms][ns][r], x2 = acc[ms][ns + 2][r];
          if (dorope) {
            int j = ns * 16 + l15;
            float invf = __expf(-(float)j * 0.28782313662f);
            float sv, cv;
            sincosf(pos * invf, &sv, &cv);
            C[i1] = x1 * cv - x2 * sv;
            C[i1 + 32] = x2 * cv + x1 * sv;
          } else {
            C[i1] = x1;
            C[i1 + 32] = x2;
          }
        }
      }
  } else {
#pragma unroll
    for (int ms = 0; ms < 4; ms++)
#pragma unroll
      for (int ns = 0; ns < 4; ns++)
#pragma unroll
        for (int r = 0; r < 4; r++) {
          int row = mBase + wm + ms * 16 + quad * 4 + r;
          int col = nBase + wn + ns * 16 + l15;
          size_t idx = (size_t)row * N + col;
          if (EPI == 0) C[idx] = acc[ms][ns][r];
          else C[idx] += acc[ms][ns][r];
        }
  }
}

// ---------------- GEMM fallback: bf16 A * fp32 W (converted in staging) ----------------
template <int EPI>
__global__ __launch_bounds__(256) void gemm_bt(const unsigned short* __restrict__ A,
                                               const float* __restrict__ W,
                                               float* __restrict__ C, int M, int N, int K) {
  __shared__ unsigned short As[128 * 40];
  __shared__ unsigned short Bs[128 * 40];
  const int tid = threadIdx.x;
  const int lane = tid & 63;
  const int w = tid >> 6;
  const int wm = (w >> 1) * 64;
  const int wn = (w & 1) * 64;
  const int l15 = lane & 15;
  const int quad = lane >> 4;
  const int q8 = quad * 8;

  const int nby = gridDim.y;
  const int nwg = gridDim.x * nby;
  const int bid = blockIdx.y * gridDim.x + blockIdx.x;
  int wk = bid;
  if ((nwg & 7) == 0) {
    int cpx = nwg >> 3;
    wk = (bid & 7) * cpx + (bid >> 3);
  }
  const int mBase = (wk % nby) * 128;
  const int nBase = (wk / nby) * 128;

  f32x4 acc[4][4] = {};

  for (int kt = 0; kt < K; kt += 32) {
    __syncthreads();
#pragma unroll
    for (int i = 0; i < 2; i++) {
      int chunk = tid + 256 * i;
      int r = chunk >> 2, cc8 = (chunk & 3) * 8;
      uint4 v = *(const uint4*)(A + (size_t)(mBase + r) * K + kt + cc8);
      *(uint4*)&As[r * 40 + cc8] = v;
    }
#pragma unroll
    for (int i = 0; i < 2; i++) {
      int chunk = tid + 256 * i;
      int r = chunk >> 2, cc8 = (chunk & 3) * 8;
      const float4* wp = (const float4*)(W + (size_t)(nBase + r) * K + kt + cc8);
      float4 f0 = wp[0], f1 = wp[1];
      uint4 v;
      v.x = f2bf(f0.x) | ((unsigned)f2bf(f0.y) << 16);
      v.y = f2bf(f0.z) | ((unsigned)f2bf(f0.w) << 16);
      v.z = f2bf(f1.x) | ((unsigned)f2bf(f1.y) << 16);
      v.w = f2bf(f1.z) | ((unsigned)f2bf(f1.w) << 16);
      *(uint4*)&Bs[r * 40 + cc8] = v;
    }
    __syncthreads();
    bf16x8 af[4], bfv[4];
#pragma unroll
    for (int ms = 0; ms < 4; ms++)
      af[ms] = *(const bf16x8*)&As[(wm + ms * 16 + l15) * 40 + q8];
#pragma unroll
    for (int ns = 0; ns < 4; ns++)
      bfv[ns] = *(const bf16x8*)&Bs[(wn + ns * 16 + l15) * 40 + q8];
#pragma unroll
    for (int ms = 0; ms < 4; ms++)
#pragma unroll
      for (int ns = 0; ns < 4; ns++)
        acc[ms][ns] = __builtin_amdgcn_mfma_f32_16x16x32_bf16(af[ms], bfv[ns], acc[ms][ns], 0, 0, 0);
  }
#pragma unroll
  for (int ms = 0; ms < 4; ms++)
#pragma unroll
    for (int ns = 0; ns < 4; ns++)
#pragma unroll
      for (int r = 0; r < 4; r++) {
        int row = mBase + wm + ms * 16 + quad * 4 + r;
        int col = nBase + wn + ns * 16 + l15;
        size_t idx = (size_t)row * N + col;
        if (EPI == 0) C[idx] = acc[ms][ns][r];
        else C[idx] += acc[ms][ns][r];
      }
}

// ---------------- flash attention (bf16 MFMA, fp32 softmax) ----------------
__global__ __launch_bounds__(256) void attn_fwd(const float* __restrict__ Q,
                                                const float* __restrict__ Kb,
                                                const float* __restrict__ Vb,
                                                unsigned short* __restrict__ O) {
  __shared__ unsigned short Qs[64 * 72];
  __shared__ unsigned short Ks[64 * 72];
  __shared__ unsigned short Vt[64 * 72];
  const int tid = threadIdx.x;
  const int lane = tid & 63;
  const int w = tid >> 6;
  const int l15 = lane & 15;
  const int quad = lane >> 4;
  const int q8 = quad * 8;
  const int bh = blockIdx.x;
  const int b = bh / NH, h = bh % NH;
  const int hkv = h >> 2;
  const int qb = blockIdx.y;

#pragma unroll
  for (int i = 0; i < 4; i++) {
    int cc = tid + 256 * i;
    int r = cc >> 4, d4 = (cc & 15) * 4;
    float4 v = *(const float4*)(Q + (size_t)(b * TT + qb * 64 + r) * QKVS + h * HD + d4);
    uint2 p;
    p.x = f2bf(v.x) | ((unsigned)f2bf(v.y) << 16);
    p.y = f2bf(v.z) | ((unsigned)f2bf(v.w) << 16);
    *(uint2*)&Qs[r * 72 + d4] = p;
  }
  __syncthreads();
  bf16x8 qa0 = *(const bf16x8*)&Qs[(w * 16 + l15) * 72 + q8];
  bf16x8 qa1 = *(const bf16x8*)&Qs[(w * 16 + l15) * 72 + 32 + q8];

  f32x4 oacc[4] = {};
  float m_i[4], l_i[4];
#pragma unroll
  for (int r = 0; r < 4; r++) { m_i[r] = -1e30f; l_i[r] = 0.f; }

  for (int kb = 0; kb <= qb; kb++) {
    __syncthreads();
#pragma unroll
    for (int i = 0; i < 4; i++) {
      int cc = tid + 256 * i;
      int r = cc >> 4, d4 = (cc & 15) * 4;
      size_t grow = (size_t)(b * TT + kb * 64 + r) * QKVS + hkv * HD + d4;
      float4 kv = *(const float4*)(Kb + grow);
      uint2 p;
      p.x = f2bf(kv.x) | ((unsigned)f2bf(kv.y) << 16);
      p.y = f2bf(kv.z) | ((unsigned)f2bf(kv.w) << 16);
      *(uint2*)&Ks[r * 72 + d4] = p;
      float4 vv = *(const float4*)(Vb + grow);
      Vt[(d4 + 0) * 72 + r] = f2bf(vv.x);
      Vt[(d4 + 1) * 72 + r] = f2bf(vv.y);
      Vt[(d4 + 2) * 72 + r] = f2bf(vv.z);
      Vt[(d4 + 3) * 72 + r] = f2bf(vv.w);
    }
    __syncthreads();
    f32x4 s[4];
#pragma unroll
    for (int ns = 0; ns < 4; ns++) {
      bf16x8 k0 = *(const bf16x8*)&Ks[(ns * 16 + l15) * 72 + q8];
      bf16x8 k1 = *(const bf16x8*)&Ks[(ns * 16 + l15) * 72 + 32 + q8];
      f32x4 z = {};
      z = __builtin_amdgcn_mfma_f32_16x16x32_bf16(qa0, k0, z, 0, 0, 0);
      s[ns] = __builtin_amdgcn_mfma_f32_16x16x32_bf16(qa1, k1, z, 0, 0, 0);
    }
#pragma unroll
    for (int ns = 0; ns < 4; ns++)
#pragma unroll
      for (int r = 0; r < 4; r++) {
        float sv = s[ns][r] * 0.125f;
        if (kb == qb) {
          int qloc = w * 16 + quad * 4 + r;
          int kloc = ns * 16 + l15;
          if (kloc > qloc) sv = -1e30f;
        }
        s[ns][r] = sv;
      }
    float p[4][4];
    float alpha[4];
#pragma unroll
    for (int r = 0; r < 4; r++) {
      float mx = fmaxf(fmaxf(s[0][r], s[1][r]), fmaxf(s[2][r], s[3][r]));
#pragma unroll
      for (int off = 1; off < 16; off <<= 1) mx = fmaxf(mx, __shfl_xor(mx, off));
      float mnew = fmaxf(m_i[r], mx);
      alpha[r] = __expf(m_i[r] - mnew);
      float rs = 0.f;
#pragma unroll
      for (int ns = 0; ns < 4; ns++) {
        p[ns][r] = __expf(s[ns][r] - mnew);
        rs += p[ns][r];
      }
#pragma unroll
      for (int off = 1; off < 16; off <<= 1) rs += __shfl_xor(rs, off);
      l_i[r] = l_i[r] * alpha[r] + rs;
      m_i[r] = mnew;
    }
#pragma unroll
    for (int ds = 0; ds < 4; ds++)
#pragma unroll
      for (int r = 0; r < 4; r++) oacc[ds][r] *= alpha[r];
#pragma unroll
    for (int ns = 0; ns < 4; ns++)
#pragma unroll
      for (int r = 0; r < 4; r++)
        Qs[(w * 16 + quad * 4 + r) * 72 + ns * 16 + l15] = f2bf(p[ns][r]);
    __syncthreads();
    bf16x8 pa0 = *(const bf16x8*)&Qs[(w * 16 + l15) * 72 + q8];
    bf16x8 pa1 = *(const bf16x8*)&Qs[(w * 16 + l15) * 72 + 32 + q8];
#pragma unroll
    for (int ds = 0; ds < 4; ds++) {
      bf16x8 v0 = *(const bf16x8*)&Vt[(ds * 16 + l15) * 72 + q8];
      bf16x8 v1 = *(const bf16x8*)&Vt[(ds * 16 + l15) * 72 + 32 + q8];
      oacc[ds] = __builtin_amdgcn_mfma_f32_16x16x32_bf16(pa0, v0, oacc[ds], 0, 0, 0);
      oacc[ds] = __builtin_amdgcn_mfma_f32_16x16x32_bf16(pa1, v1, oacc[ds], 0, 0, 0);
    }
  }
#pragma unroll
  for (int ds = 0; ds < 4; ds++)
#pragma unroll
    for (int r = 0; r < 4; r++) {
      int row = qb * 64 + w * 16 + quad * 4 + r;
      int col = h * HD + ds * 16 + l15;
      O[(size_t)(b * TT + row) * DD + col] = f2bf(oacc[ds][r] / l_i[r]);
    }
}

extern "C" void kernel_launch(void* const* d_in, const int* in_sizes, int n_in,
                              void* d_out, int out_size, void* d_ws, size_t ws_size,
                              hipStream_t stream) {
  const int* ids = (const int*)d_in[0];
  const float* emb = (const float*)d_in[1];
  const float* ln1 = (const float*)d_in[2];
  const float* qw = (const float*)d_in[3];
  const float* kw = (const float*)d_in[4];
  const float* vw = (const float*)d_in[5];
  const float* ow = (const float*)d_in[6];
  const float* ln2 = (const float*)d_in[7];
  const float* w1 = (const float*)d_in[8];
  const float* w2 = (const float*)d_in[9];
  const float* w3 = (const float*)d_in[10];
  const float* lnf = (const float*)d_in[11];

  const int BT = BB * TT;  // 2048
  const size_t MB = 1024ull * 1024ull;
  char* ob = (char*)d_out;

  float* guf = (float*)ob;                                   // 64 MiB (w2 split-K partials)
  unsigned short* hb2 = (unsigned short*)(ob + 64 * MB);     // 16 MiB [2048][4096] bf16
  unsigned short* qkvb = (unsigned short*)(ob + 80 * MB);    // 12 MiB
  unsigned short* owb = (unsigned short*)(ob + 92 * MB);     //  8 MiB
  unsigned short* w13b = (unsigned short*)(ob + 100 * MB);   // 64 MiB
  unsigned short* w2b = (unsigned short*)(ob + 164 * MB);    // 32 MiB

  char* wb = (char*)d_ws;
  unsigned short* hb = (unsigned short*)wb;  // 4 MiB
  float* x;
  float* qkv;
  unsigned short* ao;
  if (ws_size >= 28 * MB) {
    x = (float*)(wb + 4 * MB);
    qkv = (float*)(wb + 12 * MB);
    ao = (unsigned short*)(wb + 24 * MB);
  } else {
    x = (float*)(ob + 196 * MB);
    qkv = (float*)(ob + 204 * MB);
    ao = (unsigned short*)(ob + 216 * MB);
  }
  const bool bf16_logits = (ws_size >= 92 * MB);
  unsigned short* embb = bf16_logits ? (unsigned short*)(wb + 28 * MB) : nullptr;

  conv_qkv_kernel<<<6144, 256, 0, stream>>>(qw, kw, vw, qkvb);
  convw_kernel<<<4096, 256, 0, stream>>>(ow, owb);
  conv_w13_kernel<<<32768, 256, 0, stream>>>(w1, w3, w13b);
  convw_kernel<<<16384, 256, 0, stream>>>(w2, w2b);
  if (bf16_logits) convw_kernel<<<32000, 256, 0, stream>>>(emb, embb);

  embed_kernel<<<BT, 256, 0, stream>>>(ids, emb, x);
  float* p0 = guf;
  float* p1 = guf + (size_t)BT * DD;
  for (int l = 0; l < LL; l++) {
    rmsnorm_kernel<<<BT, 256, 0, stream>>>(x, ln1 + l * DD, hb);
    gemm_bb<3><<<dim3(QKVS / 128, BT / 128), 256, 0, stream>>>(
        hb, qkvb + (size_t)l * QKVS * DD, qkv, nullptr, BT, QKVS, DD);
    attn_fwd<<<dim3(BB * NH, TT / 64), 256, 0, stream>>>(qkv, qkv + 1024, qkv + 1280, ao);
    gemm_bb<1><<<dim3(DD / 128, BT / 128), 256, 0, stream>>>(
        ao, owb + (size_t)l * DD * DD, x, nullptr, BT, DD, DD);
    rmsnorm_kernel<<<BT, 256, 0, stream>>>(x, ln2 + l * DD, hb);
    gemm_8p<2><<<dim3((2 * ED) / 256, BT / 256), 512, 0, stream>>>(
        hb, w13b + (size_t)l * 2 * ED * DD, nullptr, hb2, BT, 2 * ED, DD);
    gemm_bb<0><<<dim3(DD / 128, BT / 128, 2), 256, 0, stream>>>(
        hb2, w2b + (size_t)l * DD * ED, p0, nullptr, BT, DD, ED);
    add2_kernel<<<(BT * DD / 4) / 256, 256, 0, stream>>>(x, p0, p1);
  }
  rmsnorm_kernel<<<BT, 256, 0, stream>>>(x, lnf, hb);
  if (bf16_logits) {
    gemm_8p<5><<<dim3(VV / 256, BT / 256), 512, 0, stream>>>(hb, embb, (float*)d_out, nullptr, BT, VV, DD);
  } else {
    gemm_bt<0><<<dim3(VV / 128, BT / 128), 256, 0, stream>>>(hb, emb, (float*)d_out, BT, VV, DD);
  }
}